// Round 12
// baseline (230.492 us; speedup 1.0000x reference)
//
#include <hip/hip_runtime.h>

typedef unsigned short u16;
typedef __attribute__((ext_vector_type(8))) _Float16 f16x8;
typedef __attribute__((ext_vector_type(4))) float f32x4;
typedef __attribute__((ext_vector_type(4))) unsigned short u16x4;
typedef __attribute__((ext_vector_type(8))) unsigned short u16x8;

#define MFMA16F __builtin_amdgcn_mfma_f32_16x16x32_f16

#define HW   16384
#define NCLS 150
#define NPAD 160
#define CDIM 256

// LDS strides (shorts)
#define FT2_STRIDE 136  // ftF half [64 px][128 c] (272B rows: %32B==16 spread, %16B==0 aligned)
#define KC_STRIDE 72    // clsK  [160 n][64 c]
#define FN_STRIDE 72    // featN [256 c][64 px]
#define EP_STRIDE 72    // E'    [160 n][64 px]
#define W_STRIDE  168   // E [64 px][160 n]; clsWT rows
#define CT_STRIDE 264   // combT tile [80 n][256 k]

// kSO1 LDS layout (bytes): 46080 -> 3 blocks/CU (138240 <= 163840)
#define SO_FT   0        // ftF half [64][136] u16 = 17408
#define SO_CK   17408    // clsK [160][72] u16 = 23040; E [64][168] u16 = 21504 aliases
#define SO_ROWM 40448    // [160][4] f32 = 2560
#define SO_ROWS 43008    // [160][4] f32 = 2560
#define SO_MP   45568    // [64] f32 = 256
#define SO_RZ   45824    // [64] f32 = 256
#define SO_LDS  46080

// workspace offsets (bytes)
#define WS_CLSF  0          // [8][160][256] f16
#define WS_CLSWT 655360     // [8][256][160] f16
#define WS_MG    2359296    // [8][160] f32
#define WS_RZ    2364416    // [8][160] f32
#define WS_WCF   2369536    // [256][256] f16
#define WS_COMBT 2500608    // [8][160][256] f16
#define WS_ROWP  3155968    // [8][256][160][2] f32 = 2,621,440 (part aliases after kComb)
#define WS_PART  3155968    // [8][32][256][160] f16 (written later by kOut0)
#define WS_S     24127488   // [8][160][16384] f16

__device__ __forceinline__ u16 f2h(float f){ return __builtin_bit_cast(u16, (_Float16)f); }
__device__ __forceinline__ float h2f(u16 h){ return (float)__builtin_bit_cast(_Float16, h); }

// ---------------- k0: cls -> f16 (padded 160 rows, pads zero), clsWT = (cls @ Wf^T)^T f16
__global__ __launch_bounds__(256) void k0(const float* __restrict__ cls, const float* __restrict__ Wf,
                                          u16* __restrict__ clsF, u16* __restrict__ clsWT){
  int b = blockIdx.x / NPAD, n = blockIdx.x % NPAD, t = threadIdx.x;
  __shared__ float row[256];
  int bn = b*NPAD + n;
  if (n < NCLS){
    float v = cls[(b*NCLS + n)*CDIM + t];
    clsF[bn*CDIM + t] = f2h(v);
    row[t] = v;
    __syncthreads();
    float acc = 0.f;
    const float* wr = Wf + t*CDIM;
    #pragma unroll 4
    for (int c = 0; c < 256; c += 4){
      acc += row[c]*wr[c] + row[c+1]*wr[c+1] + row[c+2]*wr[c+2] + row[c+3]*wr[c+3];
    }
    clsWT[(b*CDIM + t)*NPAD + n] = f2h(acc);
  } else {
    clsF[bn*CDIM + t] = 0;
    clsWT[(b*CDIM + t)*NPAD + n] = 0;
  }
}

// ---------------- kW: Wc f32 -> f16
__global__ __launch_bounds__(512) void kW(const float* __restrict__ Wc, u16* __restrict__ WcF){
  int i = (blockIdx.x*512 + threadIdx.x)*4;
  f32x4 v = *(const f32x4*)&Wc[i];
  u16x4 o = {f2h(v[0]), f2h(v[1]), f2h(v[2]), f2h(v[3])};
  *(u16x4*)&WcF[i] = o;
}

// ---------------- kSO1 v2: fused S-GEMM + stats + local pixel softmax + out1-GEMM.
// LDS diet (ftF K-halved, psum->shfl, f32-global residual) -> 46 KB -> 3 blocks/CU.
__global__ __launch_bounds__(512) void kSO1(const float* __restrict__ feat,
                                            const u16* __restrict__ clsF,
                                            const u16* __restrict__ clsWT,
                                            u16* __restrict__ Sg, float* __restrict__ rowP,
                                            float* __restrict__ out1){
  extern __shared__ char sm[];
  u16*  ftF  = (u16*)(sm + SO_FT);
  u16*  clsK = (u16*)(sm + SO_CK);
  u16*  E    = (u16*)(sm + SO_CK);     // alias: clsK dead after S-GEMM
  float* rowM = (float*)(sm + SO_ROWM);
  float* rowS = (float*)(sm + SO_ROWS);
  float* mpL  = (float*)(sm + SO_MP);
  float* rzL  = (float*)(sm + SO_RZ);

  int b = blockIdx.x & 7, tl = blockIdx.x >> 3, t = threadIdx.x;
  int p0 = tl*64;
  const float* featG = feat + (size_t)b*CDIM*HW;
  const u16* clsB  = clsF  + b*NPAD*CDIM;
  const u16* clsWB = clsWT + b*CDIM*NPAD;
  u16* Sb = Sg + (size_t)b*NPAD*HW;

  int lane = t & 63, wv = t >> 6;
  int l15 = lane & 15, lk = (lane >> 4) & 3;
  int nh = wv >> 2, pq = wv & 3;
  int nbase = nh*80;
  int col = pq*16 + l15;
  int cstrip = wv*32;

  // ---- S-GEMM: 2 K-halves x 2 clsK chunks, all operands staged coalesced in LDS
  f32x4 acc[5];
  #pragma unroll
  for (int f = 0; f < 5; ++f) acc[f] = (f32x4){0.f,0.f,0.f,0.f};
  for (int h = 0; h < 2; ++h){
    // stage ftF half [64 px][128 c] f32 -> f16
    {
      int p = t & 63, cg = t >> 6;
      #pragma unroll
      for (int i = 0; i < 4; ++i){
        int c0l = (i*8 + cg)*4;
        const float* g0 = featG + (size_t)(h*128 + c0l)*HW + p0 + p;
        float v0 = g0[0], v1 = g0[HW], v2 = g0[2*HW], v3 = g0[3*HW];
        u16x4 hv = {f2h(v0), f2h(v1), f2h(v2), f2h(v3)};
        *(u16x4*)&ftF[p*FT2_STRIDE + c0l] = hv;
      }
    }
    for (int q = 0; q < 2; ++q){
      // stage clsK chunk [160 n][64 c]
      #pragma unroll
      for (int it = 0; it < 3; ++it){
        int idx = it*512 + t;
        if (idx < 1280){
          int n = idx >> 3, s8 = idx & 7;
          u16x8 v = *(const u16x8*)&clsB[n*CDIM + h*128 + q*64 + s8*8];
          *(u16x8*)&clsK[n*KC_STRIDE + s8*8] = v;
        }
      }
      __syncthreads();   // ftF half (q==0) + clsK ready
      #pragma unroll
      for (int kb2 = 0; kb2 < 2; ++kb2){
        int kol = kb2*32 + lk*8;
        f16x8 bh = *(const f16x8*)&ftF[(pq*16 + l15)*FT2_STRIDE + q*64 + kol];
        #pragma unroll
        for (int f = 0; f < 5; ++f){
          f16x8 ah = *(const f16x8*)&clsK[(nbase + f*16 + l15)*KC_STRIDE + kol];
          acc[f] = MFMA16F(ah, bh, acc[f], 0, 0, 0);
        }
      }
      __syncthreads();   // clsK (and on q==1, ftF) reads done before overwrite
    }
  }
  // ---- preload clsWT fragments early (latency hides under stats/softmax phases)
  f16x8 aw0[5], aw1[5];
  #pragma unroll
  for (int kb = 0; kb < 5; ++kb){
    aw0[kb] = *(const f16x8*)&clsWB[(cstrip + l15)*NPAD + kb*32 + lk*8];
    aw1[kb] = *(const f16x8*)&clsWB[(cstrip + 16 + l15)*NPAD + kb*32 + lk*8];
  }
  #pragma unroll
  for (int kb = 0; kb < 5; ++kb){
    asm volatile("" :: "v"(aw0[kb]), "v"(aw1[kb]));
  }
  // ---- write S to global (for kOut0)
  #pragma unroll
  for (int f = 0; f < 5; ++f){
    #pragma unroll
    for (int r = 0; r < 4; ++r){
      int n = nbase + f*16 + 4*lk + r;
      Sb[(size_t)n*HW + p0 + col] = f2h(acc[f][r]);
    }
  }
  // ---- row (cls) stats: shfl-reduce (m,s) over this wave's 16 cols
  #pragma unroll
  for (int f = 0; f < 5; ++f){
    #pragma unroll
    for (int r = 0; r < 4; ++r){
      float v = acc[f][r];
      float m = v;
      m = fmaxf(m, __shfl_xor(m, 1));
      m = fmaxf(m, __shfl_xor(m, 2));
      m = fmaxf(m, __shfl_xor(m, 4));
      m = fmaxf(m, __shfl_xor(m, 8));
      float s = __expf(v - m);
      s += __shfl_xor(s, 1);
      s += __shfl_xor(s, 2);
      s += __shfl_xor(s, 4);
      s += __shfl_xor(s, 8);
      if (l15 == f){
        int n = nbase + f*16 + 4*lk + r;
        rowM[n*4 + pq] = m;
        rowS[n*4 + pq] = s;
      }
    }
  }
  // ---- write raw S^T into E (clsK dead; last K-loop barrier ordered the reads)
  #pragma unroll
  for (int f = 0; f < 5; ++f){
    u16x4 ev = {f2h(acc[f][0]), f2h(acc[f][1]), f2h(acc[f][2]), f2h(acc[f][3])};
    *(u16x4*)&E[col*W_STRIDE + nbase + f*16 + 4*lk] = ev;
  }
  __syncthreads();   // E raw + rowM/rowS ready
  // ---- combine row stats -> rowP; per-pixel max (contiguous scans, t<64)
  if (t < NPAD){
    float rm0 = rowM[t*4+0], rm1 = rowM[t*4+1], rm2 = rowM[t*4+2], rm3 = rowM[t*4+3];
    float msub = fmaxf(fmaxf(rm0, rm1), fmaxf(rm2, rm3));
    float l = rowS[t*4+0]*__expf(rm0 - msub) + rowS[t*4+1]*__expf(rm1 - msub)
            + rowS[t*4+2]*__expf(rm2 - msub) + rowS[t*4+3]*__expf(rm3 - msub);
    float* rp = rowP + ((size_t)(b*256 + tl)*NPAD + t)*2;
    rp[0] = msub;
    rp[1] = l;
  }
  if (t < 64){
    float mt = -3.0e38f;
    #pragma unroll
    for (int q = 0; q < 18; ++q){
      u16x8 v = *(const u16x8*)&E[t*W_STRIDE + q*8];
      #pragma unroll
      for (int j = 0; j < 8; ++j) mt = fmaxf(mt, h2f(v[j]));
    }
    for (int n = 144; n < NCLS; ++n) mt = fmaxf(mt, h2f(E[t*W_STRIDE + n]));
    mpL[t] = mt;
  }
  __syncthreads();   // mpL ready
  // ---- P3: raw->exp in place (512 threads); per-px sum via shfl (8 lanes/px)
  {
    int px = t >> 3, sl = t & 7;
    float mt = mpL[px];
    float s = 0.f;
    int n0 = sl*21;
    for (int n = n0; n < n0 + 21; ++n){
      float e = 0.f;
      if (n < NCLS){ e = __expf(h2f(E[px*W_STRIDE + n]) - mt); s += e; }
      if (n < NPAD) E[px*W_STRIDE + n] = f2h(e);
    }
    s += __shfl_xor(s, 1);
    s += __shfl_xor(s, 2);
    s += __shfl_xor(s, 4);
    if (sl == 0) rzL[px] = 1.0f / s;
  }
  __syncthreads();   // E(exp) + rzL ready
  // ---- out1-GEMM (A in regs, B in LDS)
  f32x4 accO[2][4];
  #pragma unroll
  for (int cf = 0; cf < 2; ++cf)
    #pragma unroll
    for (int pf = 0; pf < 4; ++pf) accO[cf][pf] = (f32x4){0.f,0.f,0.f,0.f};
  #pragma unroll
  for (int kb = 0; kb < 5; ++kb){
    int ko = kb*32 + lk*8;
    #pragma unroll
    for (int pf = 0; pf < 4; ++pf){
      f16x8 bb = *(const f16x8*)&E[(pf*16 + l15)*W_STRIDE + ko];
      accO[0][pf] = MFMA16F(aw0[kb], bb, accO[0][pf], 0, 0, 0);
      accO[1][pf] = MFMA16F(aw1[kb], bb, accO[1][pf], 0, 0, 0);
    }
  }
  // ---- epilogue: scale by 1/Z, add f32 feat residual (global, L2-hot)
  #pragma unroll
  for (int cf = 0; cf < 2; ++cf){
    #pragma unroll
    for (int r = 0; r < 4; ++r){
      int c = cstrip + cf*16 + lk*4 + r;
      const float* fr = featG + (size_t)c*HW + p0;
      float* ob = out1 + (size_t)(b*CDIM + c)*HW + p0;
      #pragma unroll
      for (int pf = 0; pf < 4; ++pf){
        int pp = pf*16 + l15;
        ob[pp] = accO[cf][pf][r]*rzL[pp] + fr[pp];
      }
    }
  }
}

// ---------------- kComb: reduce 256 tile row-partials -> m_g, rZ (2-level)
__global__ __launch_bounds__(256) void kComb(const float* __restrict__ rowP,
                                             float* __restrict__ mg, float* __restrict__ rz){
  int b = blockIdx.x / 10, nb = blockIdx.x % 10, t = threadIdx.x;
  int sg = t >> 4, j = t & 15;
  int n = nb*16 + j;
  __shared__ float pm[16][17], pl[16][17];
  float m = -3.0e38f, l = 0.f;
  for (int i = 0; i < 16; ++i){
    int s = sg*16 + i;
    const float* rp = rowP + ((size_t)(b*256 + s)*NPAD + n)*2;
    float ms = rp[0], ls = rp[1];
    float mn = fmaxf(m, ms);
    l = l*__expf(m - mn) + ls*__expf(ms - mn);
    m = mn;
  }
  pm[sg][j] = m;
  pl[sg][j] = l;
  __syncthreads();
  if (sg == 0){
    float M = pm[0][j], L = pl[0][j];
    #pragma unroll
    for (int k = 1; k < 16; ++k){
      float ms = pm[k][j], ls = pl[k][j];
      float mn = fmaxf(M, ms);
      L = L*__expf(M - mn) + ls*__expf(ms - mn);
      M = mn;
    }
    mg[b*NPAD + n] = M;
    rz[b*NPAD + n] = 1.0f / L;
  }
}

// ---------------- kOut0: part[c][n] = sum_p featF16[c][p] * exp(S - m_g[n])  (512 px/block)
__global__ __launch_bounds__(512) void kOut0(const u16* __restrict__ Sg, const float* __restrict__ feat,
                                             const float* __restrict__ mg, u16* __restrict__ part){
  extern __shared__ char sm[];
  u16* Ep = (u16*)sm;                        // [NPAD][EP_STRIDE]
  u16* fN = (u16*)(sm + NPAD*EP_STRIDE*2);   // [CDIM][FN_STRIDE]
  int b = blockIdx.x & 7, pr = blockIdx.x >> 3, t = threadIdx.x;
  const u16* Sb = Sg + (size_t)b*NPAD*HW;
  const float* featB = feat + (size_t)b*CDIM*HW;
  const float* mgB = mg + b*NPAD;
  int lane = t & 63, wv = t >> 6;
  int l15 = lane & 15, lk = (lane >> 4) & 3;
  int cstrip = wv*32;
  int rr = t >> 3, px8 = (t & 7)*8;
  f32x4 acc[2][10];
  #pragma unroll
  for (int cf = 0; cf < 2; ++cf)
    #pragma unroll
    for (int nf = 0; nf < 10; ++nf) acc[cf][nf] = (f32x4){0.f,0.f,0.f,0.f};
  for (int ck = 0; ck < 8; ++ck){
    int p0 = pr*512 + ck*64;
    #pragma unroll
    for (int ps = 0; ps < 3; ++ps){
      int rowi = ps*64 + rr;
      if (rowi < NPAD){
        u16x8 v = *(const u16x8*)&Sb[(size_t)rowi*HW + p0 + px8];
        float m = mgB[rowi];
        u16x8 o;
        #pragma unroll
        for (int j = 0; j < 8; ++j) o[j] = f2h(__expf(h2f(v[j]) - m));
        *(u16x8*)&Ep[rowi*EP_STRIDE + px8] = o;
      }
    }
    #pragma unroll
    for (int ps = 0; ps < 4; ++ps){
      int c = ps*64 + rr;
      const float* g = featB + (size_t)c*HW + p0 + px8;
      f32x4 v0 = *(const f32x4*)&g[0];
      f32x4 v1 = *(const f32x4*)&g[4];
      u16x8 o = {f2h(v0[0]), f2h(v0[1]), f2h(v0[2]), f2h(v0[3]),
                 f2h(v1[0]), f2h(v1[1]), f2h(v1[2]), f2h(v1[3])};
      *(u16x8*)&fN[c*FN_STRIDE + px8] = o;
    }
    __syncthreads();
    #pragma unroll
    for (int kb = 0; kb < 2; ++kb){
      int ko = kb*32 + lk*8;
      f16x8 a0 = *(const f16x8*)&fN[(cstrip + l15)*FN_STRIDE + ko];
      f16x8 a1 = *(const f16x8*)&fN[(cstrip + 16 + l15)*FN_STRIDE + ko];
      #pragma unroll
      for (int nf = 0; nf < 10; ++nf){
        f16x8 bb = *(const f16x8*)&Ep[(nf*16 + l15)*EP_STRIDE + ko];
        acc[0][nf] = MFMA16F(a0, bb, acc[0][nf], 0, 0, 0);
        acc[1][nf] = MFMA16F(a1, bb, acc[1][nf], 0, 0, 0);
      }
    }
    __syncthreads();
  }
  #pragma unroll
  for (int cf = 0; cf < 2; ++cf){
    #pragma unroll
    for (int nf = 0; nf < 10; ++nf){
      #pragma unroll
      for (int r = 0; r < 4; ++r){
        int c = cstrip + cf*16 + lk*4 + r;
        int n = nf*16 + l15;
        part[((size_t)(b*32 + pr)*CDIM + c)*NPAD + n] = f2h(acc[cf][nf][r]);
      }
    }
  }
}

// ---------------- k4a: streaming reduce of part over 32 chunks, fold rZ -> combT[b][n][c] f16
__global__ __launch_bounds__(256) void k4a(const u16* __restrict__ part, const float* __restrict__ rz,
                                           u16* __restrict__ combT){
  int b = blockIdx.x / 20, sub = blockIdx.x % 20, t = threadIdx.x;
  int idx8 = (sub*256 + t)*8;
  int c = idx8 / NPAD, n0 = idx8 % NPAD;
  const u16* base = part + (size_t)(b*32)*CDIM*NPAD + idx8;
  float a[8];
  #pragma unroll
  for (int j = 0; j < 8; ++j) a[j] = 0.f;
  for (int s = 0; s < 32; ++s){
    u16x8 v = *(const u16x8*)&base[(size_t)s*CDIM*NPAD];
    #pragma unroll
    for (int j = 0; j < 8; ++j) a[j] += h2f(v[j]);
  }
  const float* rzB = rz + b*NPAD + n0;
  #pragma unroll
  for (int j = 0; j < 8; ++j){
    combT[((size_t)(b*NPAD) + n0 + j)*CDIM + c] = f2h(a[j] * rzB[j]);
  }
}

// ---------------- k4b: out0[n][c] = cls + combT[n][:] @ WcF[c][:]  (MFMA, 80 n-rows/block)
__global__ __launch_bounds__(512) void k4b(const u16* __restrict__ combT, const u16* __restrict__ WcF,
                                           const float* __restrict__ cls, float* __restrict__ out0){
  extern __shared__ char sm[];
  u16* A = (u16*)sm;   // [80][CT_STRIDE]
  int b = blockIdx.x >> 1, nb = blockIdx.x & 1, t = threadIdx.x;
  const u16* cb = combT + (size_t)(b*NPAD + nb*80)*CDIM;
  #pragma unroll
  for (int it = 0; it < 10; ++it){
    int idx8 = (it*512 + t)*8;
    if (idx8 < 80*256){
      int row = idx8 >> 8, k0 = idx8 & 255;
      u16x8 v = *(const u16x8*)&cb[idx8];
      *(u16x8*)&A[row*CT_STRIDE + k0] = v;
    }
  }
  __syncthreads();
  int lane = t & 63, wv = t >> 6;
  int l15 = lane & 15, lk = (lane >> 4) & 3;
  int cstrip = wv*32;
  f32x4 acc[5][2];
  #pragma unroll
  for (int f = 0; f < 5; ++f)
    #pragma unroll
    for (int ct = 0; ct < 2; ++ct) acc[f][ct] = (f32x4){0.f,0.f,0.f,0.f};
  #pragma unroll
  for (int kb = 0; kb < 8; ++kb){
    int ko = kb*32 + lk*8;
    f16x8 b0 = *(const f16x8*)&WcF[(cstrip + l15)*CDIM + ko];
    f16x8 b1 = *(const f16x8*)&WcF[(cstrip + 16 + l15)*CDIM + ko];
    #pragma unroll
    for (int f = 0; f < 5; ++f){
      f16x8 af = *(const f16x8*)&A[(f*16 + l15)*CT_STRIDE + ko];
      acc[f][0] = MFMA16F(af, b0, acc[f][0], 0, 0, 0);
      acc[f][1] = MFMA16F(af, b1, acc[f][1], 0, 0, 0);
    }
  }
  #pragma unroll
  for (int f = 0; f < 5; ++f){
    #pragma unroll
    for (int r = 0; r < 4; ++r){
      int n = nb*80 + f*16 + lk*4 + r;
      if (n < NCLS){
        #pragma unroll
        for (int ct = 0; ct < 2; ++ct){
          int c = cstrip + ct*16 + l15;
          out0[(size_t)(b*NCLS + n)*CDIM + c] = cls[(size_t)(b*NCLS + n)*CDIM + c] + acc[f][ct][r];
        }
      }
    }
  }
}

extern "C" void kernel_launch(void* const* d_in, const int* in_sizes, int n_in,
                              void* d_out, int out_size, void* d_ws, size_t ws_size,
                              hipStream_t stream){
  (void)in_sizes; (void)n_in; (void)out_size; (void)ws_size;
  const float* cls  = (const float*)d_in[0];   // [8][150][256]
  const float* feat = (const float*)d_in[1];   // [8][256][16384]
  const float* Wc   = (const float*)d_in[2];   // [256][256]
  const float* Wf   = (const float*)d_in[3];   // [256][256]
  float* out0 = (float*)d_out;                 // [8][150][256]
  float* out1 = out0 + 8*NCLS*CDIM;            // [8][256][16384]
  char* ws = (char*)d_ws;
  u16*   clsF   = (u16*)(ws + WS_CLSF);
  u16*   clsWT  = (u16*)(ws + WS_CLSWT);
  float* mgv    = (float*)(ws + WS_MG);
  float* rzv    = (float*)(ws + WS_RZ);
  u16*   WcFv   = (u16*)(ws + WS_WCF);
  u16*   combTv = (u16*)(ws + WS_COMBT);
  float* rowPv  = (float*)(ws + WS_ROWP);
  u16*   partv  = (u16*)(ws + WS_PART);
  u16*   Sgp    = (u16*)(ws + WS_S);

  hipFuncSetAttribute((const void*)kSO1, hipFuncAttributeMaxDynamicSharedMemorySize, SO_LDS);

  k0   <<<8*NPAD, 256, 0, stream>>>(cls, Wf, clsF, clsWT);
  kW   <<<32, 512, 0, stream>>>(Wc, WcFv);
  kSO1 <<<2048, 512, SO_LDS, stream>>>(feat, clsF, clsWT, Sgp, rowPv, out1);
  kComb<<<80, 256, 0, stream>>>(rowPv, mgv, rzv);
  kOut0<<<256, 512, (NPAD*EP_STRIDE + CDIM*FN_STRIDE)*2, stream>>>(Sgp, feat, mgv, partv);
  k4a  <<<160, 256, 0, stream>>>(partv, rzv, combTv);
  k4b  <<<16, 512, 80*CT_STRIDE*2, stream>>>(combTv, WcFv, cls, out0);
}

// Round 13
// 220.825 us; speedup vs baseline: 1.0438x; 1.0438x over previous
//
#include <hip/hip_runtime.h>

typedef unsigned short u16;
typedef __attribute__((ext_vector_type(8))) _Float16 f16x8;
typedef __attribute__((ext_vector_type(4))) float f32x4;
typedef __attribute__((ext_vector_type(4))) unsigned short u16x4;
typedef __attribute__((ext_vector_type(8))) unsigned short u16x8;

#define MFMA16F __builtin_amdgcn_mfma_f32_16x16x32_f16

#define HW   16384
#define NCLS 150
#define NPAD 160
#define CDIM 256

// LDS strides (shorts)
#define FT_STRIDE 264   // ftF [64 px][256 c]
#define KC_STRIDE 72    // clsK  [160 n][64 c]
#define FN_STRIDE 72    // featN [256 c][64 px]
#define EP_STRIDE 72    // E'    [160 n][64 px]
#define W_STRIDE  168   // E [64 px][160 n]; clsWT rows
#define CT_STRIDE 264   // combT tile [80 n][256 k]

// kSO1 LDS layout (bytes): 63488 -> 2 blocks/CU
#define SO_FT   0        // ftF [64][264] u16 = 33792
#define SO_CK   33792    // clsK [160][72] u16 = 23040; E [64][168] u16 = 21504 aliases
#define SO_ROWM 56832    // [160][4] f32 = 2560
#define SO_ROWS 59392    // [160][4] f32 = 2560... (note: rowS only needs [160][4])
#define SO_PMX  61952    // [2][64] f32 = 512
#define SO_PZS  62464    // [2][64] f32 = 512
#define SO_RZ   62976    // [64] f32 = 256
#define SO_LDS  63232

// workspace offsets (bytes)
#define WS_CLSF  0          // [8][160][256] f16
#define WS_CLSWT 655360     // [8][256][160] f16
#define WS_MG    2359296    // [8][160] f32
#define WS_RZ    2364416    // [8][160] f32
#define WS_WCF   2369536    // [256][256] f16
#define WS_COMBT 2500608    // [8][160][256] f16
#define WS_ROWP  3155968    // [8][256][160][2] f32 = 2,621,440 (part aliases after kComb)
#define WS_PART  3155968    // [8][32][256][160] f16 (written later by kOut0)
#define WS_S     24127488   // [8][160][16384] f16

__device__ __forceinline__ u16 f2h(float f){ return __builtin_bit_cast(u16, (_Float16)f); }
__device__ __forceinline__ float h2f(u16 h){ return (float)__builtin_bit_cast(_Float16, h); }

// ---------------- k0: cls -> f16 (padded 160 rows, pads zero), clsWT = (cls @ Wf^T)^T f16
__global__ __launch_bounds__(256) void k0(const float* __restrict__ cls, const float* __restrict__ Wf,
                                          u16* __restrict__ clsF, u16* __restrict__ clsWT){
  int b = blockIdx.x / NPAD, n = blockIdx.x % NPAD, t = threadIdx.x;
  __shared__ float row[256];
  int bn = b*NPAD + n;
  if (n < NCLS){
    float v = cls[(b*NCLS + n)*CDIM + t];
    clsF[bn*CDIM + t] = f2h(v);
    row[t] = v;
    __syncthreads();
    float acc = 0.f;
    const float* wr = Wf + t*CDIM;
    #pragma unroll 4
    for (int c = 0; c < 256; c += 4){
      acc += row[c]*wr[c] + row[c+1]*wr[c+1] + row[c+2]*wr[c+2] + row[c+3]*wr[c+3];
    }
    clsWT[(b*CDIM + t)*NPAD + n] = f2h(acc);
  } else {
    clsF[bn*CDIM + t] = 0;
    clsWT[(b*CDIM + t)*NPAD + n] = 0;
  }
}

// ---------------- kW: Wc f32 -> f16
__global__ __launch_bounds__(512) void kW(const float* __restrict__ Wc, u16* __restrict__ WcF){
  int i = (blockIdx.x*512 + threadIdx.x)*4;
  f32x4 v = *(const f32x4*)&Wc[i];
  u16x4 o = {f2h(v[0]), f2h(v[1]), f2h(v[2]), f2h(v[3])};
  *(u16x4*)&WcF[i] = o;
}

// ---------------- kSO1 v3: r11 base + in-register pixel softmax (no serial P2/P3 phases).
// Each lane owns ONE pixel column with 20/160 n-values -> px stats via in-lane + shfl reduce.
__global__ __launch_bounds__(512) void kSO1(const float* __restrict__ feat,
                                            const u16* __restrict__ clsF,
                                            const u16* __restrict__ clsWT,
                                            u16* __restrict__ Sg, float* __restrict__ rowP,
                                            float* __restrict__ out1){
  extern __shared__ char sm[];
  u16*  ftF  = (u16*)(sm + SO_FT);
  u16*  clsK = (u16*)(sm + SO_CK);
  u16*  E    = (u16*)(sm + SO_CK);     // alias: clsK dead after S-GEMM
  float* rowM = (float*)(sm + SO_ROWM);
  float* rowS = (float*)(sm + SO_ROWS);
  float* pmx  = (float*)(sm + SO_PMX);
  float* pzs  = (float*)(sm + SO_PZS);
  float* rzL  = (float*)(sm + SO_RZ);

  int b = blockIdx.x & 7, tl = blockIdx.x >> 3, t = threadIdx.x;
  int p0 = tl*64;
  const float* featG = feat + (size_t)b*CDIM*HW;
  const u16* clsB  = clsF  + b*NPAD*CDIM;
  const u16* clsWB = clsWT + b*CDIM*NPAD;
  u16* Sb = Sg + (size_t)b*NPAD*HW;

  int lane = t & 63, wv = t >> 6;
  int l15 = lane & 15, lk = (lane >> 4) & 3;
  int nh = wv >> 2, pq = wv & 3;
  int nbase = nh*80;
  int col = pq*16 + l15;
  int cstrip = wv*32;

  // ---- stage ftF [64px][256c] f32->f16 (once)
  {
    int p = t & 63, cg = t >> 6;
    #pragma unroll
    for (int i = 0; i < 8; ++i){
      int c0 = (i*8 + cg)*4;
      const float* g0 = featG + (size_t)c0*HW + p0 + p;
      float v0 = g0[0], v1 = g0[HW], v2 = g0[2*HW], v3 = g0[3*HW];
      u16x4 hv = {f2h(v0), f2h(v1), f2h(v2), f2h(v3)};
      *(u16x4*)&ftF[p*FT_STRIDE + c0] = hv;
    }
  }
  // ---- S-GEMM: K-loop, cls chunk staged to LDS (coalesced, parallel)
  f32x4 acc[5];
  #pragma unroll
  for (int f = 0; f < 5; ++f) acc[f] = (f32x4){0.f,0.f,0.f,0.f};
  for (int kc = 0; kc < 4; ++kc){
    #pragma unroll
    for (int it = 0; it < 3; ++it){
      int idx = it*512 + t;
      if (idx < 1280){
        int n = idx >> 3, s8 = idx & 7;
        u16x8 v = *(const u16x8*)&clsB[n*CDIM + kc*64 + s8*8];
        *(u16x8*)&clsK[n*KC_STRIDE + s8*8] = v;
      }
    }
    __syncthreads();   // clsK (and on kc=0, ftF) ready
    #pragma unroll
    for (int kb2 = 0; kb2 < 2; ++kb2){
      int kol = kb2*32 + lk*8;
      f16x8 bh = *(const f16x8*)&ftF[(pq*16 + l15)*FT_STRIDE + kc*64 + kol];
      #pragma unroll
      for (int f = 0; f < 5; ++f){
        f16x8 ah = *(const f16x8*)&clsK[(nbase + f*16 + l15)*KC_STRIDE + kol];
        acc[f] = MFMA16F(ah, bh, acc[f], 0, 0, 0);
      }
    }
    __syncthreads();   // clsK reads done before next-stage overwrite
  }
  // ---- preload clsWT fragments early (latency hides under stats phases)
  f16x8 aw0[5], aw1[5];
  #pragma unroll
  for (int kb = 0; kb < 5; ++kb){
    aw0[kb] = *(const f16x8*)&clsWB[(cstrip + l15)*NPAD + kb*32 + lk*8];
    aw1[kb] = *(const f16x8*)&clsWB[(cstrip + 16 + l15)*NPAD + kb*32 + lk*8];
  }
  #pragma unroll
  for (int kb = 0; kb < 5; ++kb){
    asm volatile("" :: "v"(aw0[kb]), "v"(aw1[kb]));
  }
  // ---- write S to global (for kOut0)
  #pragma unroll
  for (int f = 0; f < 5; ++f){
    #pragma unroll
    for (int r = 0; r < 4; ++r){
      int n = nbase + f*16 + 4*lk + r;
      Sb[(size_t)n*HW + p0 + col] = f2h(acc[f][r]);
    }
  }
  // ---- row (cls) stats: shfl-reduce (m,s) over this wave's 16 cols
  #pragma unroll
  for (int f = 0; f < 5; ++f){
    #pragma unroll
    for (int r = 0; r < 4; ++r){
      float v = acc[f][r];
      float m = v;
      m = fmaxf(m, __shfl_xor(m, 1));
      m = fmaxf(m, __shfl_xor(m, 2));
      m = fmaxf(m, __shfl_xor(m, 4));
      m = fmaxf(m, __shfl_xor(m, 8));
      float s = __expf(v - m);
      s += __shfl_xor(s, 1);
      s += __shfl_xor(s, 2);
      s += __shfl_xor(s, 4);
      s += __shfl_xor(s, 8);
      if (l15 == f){
        int n = nbase + f*16 + 4*lk + r;
        rowM[n*4 + pq] = m;
        rowS[n*4 + pq] = s;
      }
    }
  }
  // ---- pixel (pos) max: in-lane over 20 vals + shfl over lk -> pmx[nh][col]
  {
    float pmax = -3.0e38f;
    #pragma unroll
    for (int f = 0; f < 5; ++f)
      #pragma unroll
      for (int r = 0; r < 4; ++r){
        int n = nbase + 16*f + 4*lk + r;
        if (n < NCLS) pmax = fmaxf(pmax, acc[f][r]);
      }
    pmax = fmaxf(pmax, __shfl_xor(pmax, 16));
    pmax = fmaxf(pmax, __shfl_xor(pmax, 32));
    if (lk == 0) pmx[nh*64 + col] = pmax;
  }
  __syncthreads();   // B9: pmx + rowM/rowS + E-region free
  // ---- combine row stats -> rowP (t<160)
  if (t < NPAD){
    float rm0 = rowM[t*4+0], rm1 = rowM[t*4+1], rm2 = rowM[t*4+2], rm3 = rowM[t*4+3];
    float msub = fmaxf(fmaxf(rm0, rm1), fmaxf(rm2, rm3));
    float l = rowS[t*4+0]*__expf(rm0 - msub) + rowS[t*4+1]*__expf(rm1 - msub)
            + rowS[t*4+2]*__expf(rm2 - msub) + rowS[t*4+3]*__expf(rm3 - msub);
    float* rp = rowP + ((size_t)(b*256 + tl)*NPAD + t)*2;
    rp[0] = msub;
    rp[1] = l;
  }
  // ---- exp in-register, write E^T (already exponentiated), z-reduce -> pzs
  {
    float mp_ = fmaxf(pmx[col], pmx[64 + col]);
    float s = 0.f;
    #pragma unroll
    for (int f = 0; f < 5; ++f){
      u16x4 ev;
      #pragma unroll
      for (int r = 0; r < 4; ++r){
        int n = nbase + 16*f + 4*lk + r;
        float e = (n < NCLS) ? __expf(acc[f][r] - mp_) : 0.f;
        s += e;
        ev[r] = f2h(e);
      }
      *(u16x4*)&E[col*W_STRIDE + nbase + 16*f + 4*lk] = ev;
    }
    s += __shfl_xor(s, 16);
    s += __shfl_xor(s, 32);
    if (lk == 0) pzs[nh*64 + col] = s;
  }
  __syncthreads();   // B10: E(exp) + pzs ready
  // ---- rz (t<64) concurrent with out1-GEMM
  if (t < 64) rzL[t] = 1.0f / (pzs[t] + pzs[64 + t]);
  f32x4 accO[2][4];
  #pragma unroll
  for (int cf = 0; cf < 2; ++cf)
    #pragma unroll
    for (int pf = 0; pf < 4; ++pf) accO[cf][pf] = (f32x4){0.f,0.f,0.f,0.f};
  #pragma unroll
  for (int kb = 0; kb < 5; ++kb){
    int ko = kb*32 + lk*8;
    #pragma unroll
    for (int pf = 0; pf < 4; ++pf){
      f16x8 bb = *(const f16x8*)&E[(pf*16 + l15)*W_STRIDE + ko];
      accO[0][pf] = MFMA16F(aw0[kb], bb, accO[0][pf], 0, 0, 0);
      accO[1][pf] = MFMA16F(aw1[kb], bb, accO[1][pf], 0, 0, 0);
    }
  }
  __syncthreads();   // B11: rzL visible
  // ---- epilogue: scale by 1/Z, add f16 feat residual from ftF (still resident)
  #pragma unroll
  for (int cf = 0; cf < 2; ++cf){
    #pragma unroll
    for (int r = 0; r < 4; ++r){
      int c = cstrip + cf*16 + lk*4 + r;
      float* ob = out1 + (size_t)(b*CDIM + c)*HW + p0;
      #pragma unroll
      for (int pf = 0; pf < 4; ++pf){
        int pp = pf*16 + l15;
        ob[pp] = accO[cf][pf][r]*rzL[pp] + h2f(ftF[pp*FT_STRIDE + c]);
      }
    }
  }
}

// ---------------- kComb: reduce 256 tile row-partials -> m_g, rZ (2-level)
__global__ __launch_bounds__(256) void kComb(const float* __restrict__ rowP,
                                             float* __restrict__ mg, float* __restrict__ rz){
  int b = blockIdx.x / 10, nb = blockIdx.x % 10, t = threadIdx.x;
  int sg = t >> 4, j = t & 15;
  int n = nb*16 + j;
  __shared__ float pm[16][17], pl[16][17];
  float m = -3.0e38f, l = 0.f;
  for (int i = 0; i < 16; ++i){
    int s = sg*16 + i;
    const float* rp = rowP + ((size_t)(b*256 + s)*NPAD + n)*2;
    float ms = rp[0], ls = rp[1];
    float mn = fmaxf(m, ms);
    l = l*__expf(m - mn) + ls*__expf(ms - mn);
    m = mn;
  }
  pm[sg][j] = m;
  pl[sg][j] = l;
  __syncthreads();
  if (sg == 0){
    float M = pm[0][j], L = pl[0][j];
    #pragma unroll
    for (int k = 1; k < 16; ++k){
      float ms = pm[k][j], ls = pl[k][j];
      float mn = fmaxf(M, ms);
      L = L*__expf(M - mn) + ls*__expf(ms - mn);
      M = mn;
    }
    mg[b*NPAD + n] = M;
    rz[b*NPAD + n] = 1.0f / L;
  }
}

// ---------------- kOut0: part[c][n] = sum_p featF16[c][p] * exp(S - m_g[n])  (512 px/block)
__global__ __launch_bounds__(512) void kOut0(const u16* __restrict__ Sg, const float* __restrict__ feat,
                                             const float* __restrict__ mg, u16* __restrict__ part){
  extern __shared__ char sm[];
  u16* Ep = (u16*)sm;                        // [NPAD][EP_STRIDE]
  u16* fN = (u16*)(sm + NPAD*EP_STRIDE*2);   // [CDIM][FN_STRIDE]
  int b = blockIdx.x & 7, pr = blockIdx.x >> 3, t = threadIdx.x;
  const u16* Sb = Sg + (size_t)b*NPAD*HW;
  const float* featB = feat + (size_t)b*CDIM*HW;
  const float* mgB = mg + b*NPAD;
  int lane = t & 63, wv = t >> 6;
  int l15 = lane & 15, lk = (lane >> 4) & 3;
  int cstrip = wv*32;
  int rr = t >> 3, px8 = (t & 7)*8;
  f32x4 acc[2][10];
  #pragma unroll
  for (int cf = 0; cf < 2; ++cf)
    #pragma unroll
    for (int nf = 0; nf < 10; ++nf) acc[cf][nf] = (f32x4){0.f,0.f,0.f,0.f};
  for (int ck = 0; ck < 8; ++ck){
    int p0 = pr*512 + ck*64;
    #pragma unroll
    for (int ps = 0; ps < 3; ++ps){
      int rowi = ps*64 + rr;
      if (rowi < NPAD){
        u16x8 v = *(const u16x8*)&Sb[(size_t)rowi*HW + p0 + px8];
        float m = mgB[rowi];
        u16x8 o;
        #pragma unroll
        for (int j = 0; j < 8; ++j) o[j] = f2h(__expf(h2f(v[j]) - m));
        *(u16x8*)&Ep[rowi*EP_STRIDE + px8] = o;
      }
    }
    #pragma unroll
    for (int ps = 0; ps < 4; ++ps){
      int c = ps*64 + rr;
      const float* g = featB + (size_t)c*HW + p0 + px8;
      f32x4 v0 = *(const f32x4*)&g[0];
      f32x4 v1 = *(const f32x4*)&g[4];
      u16x8 o = {f2h(v0[0]), f2h(v0[1]), f2h(v0[2]), f2h(v0[3]),
                 f2h(v1[0]), f2h(v1[1]), f2h(v1[2]), f2h(v1[3])};
      *(u16x8*)&fN[c*FN_STRIDE + px8] = o;
    }
    __syncthreads();
    #pragma unroll
    for (int kb = 0; kb < 2; ++kb){
      int ko = kb*32 + lk*8;
      f16x8 a0 = *(const f16x8*)&fN[(cstrip + l15)*FN_STRIDE + ko];
      f16x8 a1 = *(const f16x8*)&fN[(cstrip + 16 + l15)*FN_STRIDE + ko];
      #pragma unroll
      for (int nf = 0; nf < 10; ++nf){
        f16x8 bb = *(const f16x8*)&Ep[(nf*16 + l15)*EP_STRIDE + ko];
        acc[0][nf] = MFMA16F(a0, bb, acc[0][nf], 0, 0, 0);
        acc[1][nf] = MFMA16F(a1, bb, acc[1][nf], 0, 0, 0);
      }
    }
    __syncthreads();
  }
  #pragma unroll
  for (int cf = 0; cf < 2; ++cf){
    #pragma unroll
    for (int nf = 0; nf < 10; ++nf){
      #pragma unroll
      for (int r = 0; r < 4; ++r){
        int c = cstrip + cf*16 + lk*4 + r;
        int n = nf*16 + l15;
        part[((size_t)(b*32 + pr)*CDIM + c)*NPAD + n] = f2h(acc[cf][nf][r]);
      }
    }
  }
}

// ---------------- k4a: streaming reduce of part over 32 chunks, fold rZ -> combT[b][n][c] f16
__global__ __launch_bounds__(256) void k4a(const u16* __restrict__ part, const float* __restrict__ rz,
                                           u16* __restrict__ combT){
  int b = blockIdx.x / 20, sub = blockIdx.x % 20, t = threadIdx.x;
  int idx8 = (sub*256 + t)*8;
  int c = idx8 / NPAD, n0 = idx8 % NPAD;
  const u16* base = part + (size_t)(b*32)*CDIM*NPAD + idx8;
  float a[8];
  #pragma unroll
  for (int j = 0; j < 8; ++j) a[j] = 0.f;
  for (int s = 0; s < 32; ++s){
    u16x8 v = *(const u16x8*)&base[(size_t)s*CDIM*NPAD];
    #pragma unroll
    for (int j = 0; j < 8; ++j) a[j] += h2f(v[j]);
  }
  const float* rzB = rz + b*NPAD + n0;
  #pragma unroll
  for (int j = 0; j < 8; ++j){
    combT[((size_t)(b*NPAD) + n0 + j)*CDIM + c] = f2h(a[j] * rzB[j]);
  }
}

// ---------------- k4b: out0[n][c] = cls + combT[n][:] @ WcF[c][:]  (MFMA, 80 n-rows/block)
__global__ __launch_bounds__(512) void k4b(const u16* __restrict__ combT, const u16* __restrict__ WcF,
                                           const float* __restrict__ cls, float* __restrict__ out0){
  extern __shared__ char sm[];
  u16* A = (u16*)sm;   // [80][CT_STRIDE]
  int b = blockIdx.x >> 1, nb = blockIdx.x & 1, t = threadIdx.x;
  const u16* cb = combT + (size_t)(b*NPAD + nb*80)*CDIM;
  #pragma unroll
  for (int it = 0; it < 10; ++it){
    int idx8 = (it*512 + t)*8;
    if (idx8 < 80*256){
      int row = idx8 >> 8, k0 = idx8 & 255;
      u16x8 v = *(const u16x8*)&cb[idx8];
      *(u16x8*)&A[row*CT_STRIDE + k0] = v;
    }
  }
  __syncthreads();
  int lane = t & 63, wv = t >> 6;
  int l15 = lane & 15, lk = (lane >> 4) & 3;
  int cstrip = wv*32;
  f32x4 acc[5][2];
  #pragma unroll
  for (int f = 0; f < 5; ++f)
    #pragma unroll
    for (int ct = 0; ct < 2; ++ct) acc[f][ct] = (f32x4){0.f,0.f,0.f,0.f};
  #pragma unroll
  for (int kb = 0; kb < 8; ++kb){
    int ko = kb*32 + lk*8;
    f16x8 b0 = *(const f16x8*)&WcF[(cstrip + l15)*CDIM + ko];
    f16x8 b1 = *(const f16x8*)&WcF[(cstrip + 16 + l15)*CDIM + ko];
    #pragma unroll
    for (int f = 0; f < 5; ++f){
      f16x8 af = *(const f16x8*)&A[(f*16 + l15)*CT_STRIDE + ko];
      acc[f][0] = MFMA16F(af, b0, acc[f][0], 0, 0, 0);
      acc[f][1] = MFMA16F(af, b1, acc[f][1], 0, 0, 0);
    }
  }
  #pragma unroll
  for (int f = 0; f < 5; ++f){
    #pragma unroll
    for (int r = 0; r < 4; ++r){
      int n = nb*80 + f*16 + lk*4 + r;
      if (n < NCLS){
        #pragma unroll
        for (int ct = 0; ct < 2; ++ct){
          int c = cstrip + ct*16 + l15;
          out0[(size_t)(b*NCLS + n)*CDIM + c] = cls[(size_t)(b*NCLS + n)*CDIM + c] + acc[f][ct][r];
        }
      }
    }
  }
}

extern "C" void kernel_launch(void* const* d_in, const int* in_sizes, int n_in,
                              void* d_out, int out_size, void* d_ws, size_t ws_size,
                              hipStream_t stream){
  (void)in_sizes; (void)n_in; (void)out_size; (void)ws_size;
  const float* cls  = (const float*)d_in[0];   // [8][150][256]
  const float* feat = (const float*)d_in[1];   // [8][256][16384]
  const float* Wc   = (const float*)d_in[2];   // [256][256]
  const float* Wf   = (const float*)d_in[3];   // [256][256]
  float* out0 = (float*)d_out;                 // [8][150][256]
  float* out1 = out0 + 8*NCLS*CDIM;            // [8][256][16384]
  char* ws = (char*)d_ws;
  u16*   clsF   = (u16*)(ws + WS_CLSF);
  u16*   clsWT  = (u16*)(ws + WS_CLSWT);
  float* mgv    = (float*)(ws + WS_MG);
  float* rzv    = (float*)(ws + WS_RZ);
  u16*   WcFv   = (u16*)(ws + WS_WCF);
  u16*   combTv = (u16*)(ws + WS_COMBT);
  float* rowPv  = (float*)(ws + WS_ROWP);
  u16*   partv  = (u16*)(ws + WS_PART);
  u16*   Sgp    = (u16*)(ws + WS_S);

  hipFuncSetAttribute((const void*)kSO1, hipFuncAttributeMaxDynamicSharedMemorySize, SO_LDS);

  k0   <<<8*NPAD, 256, 0, stream>>>(cls, Wf, clsF, clsWT);
  kW   <<<32, 512, 0, stream>>>(Wc, WcFv);
  kSO1 <<<2048, 512, SO_LDS, stream>>>(feat, clsF, clsWT, Sgp, rowPv, out1);
  kComb<<<80, 256, 0, stream>>>(rowPv, mgv, rzv);
  kOut0<<<256, 512, (NPAD*EP_STRIDE + CDIM*FN_STRIDE)*2, stream>>>(Sgp, feat, mgv, partv);
  k4a  <<<160, 256, 0, stream>>>(partv, rzv, combTv);
  k4b  <<<16, 512, 80*CT_STRIDE*2, stream>>>(combTv, WcFv, cls, out0);
}

// Round 15
// 195.240 us; speedup vs baseline: 1.1806x; 1.1310x over previous
//
#include <hip/hip_runtime.h>

typedef unsigned short u16;
typedef __attribute__((ext_vector_type(8))) _Float16 f16x8;
typedef __attribute__((ext_vector_type(2))) _Float16 f16x2;
typedef __attribute__((ext_vector_type(4))) float f32x4;
typedef __attribute__((ext_vector_type(4))) unsigned short u16x4;
typedef __attribute__((ext_vector_type(8))) unsigned short u16x8;

#define MFMA16F __builtin_amdgcn_mfma_f32_16x16x32_f16

#define HW   16384
#define NCLS 150
#define NPAD 160
#define CDIM 256

// LDS strides (shorts)
#define FT_STRIDE 264   // ftF [64 px][256 c]
#define KC_STRIDE 72    // clsK  [160 n][64 c]
#define FN_STRIDE 72    // featN [c][64 px]
#define EP_STRIDE 72    // E'    [160 n][64 px]
#define W_STRIDE  168   // E [64 px][160 n]; clsWT rows
#define CT_STRIDE 264   // combT tile [80 n][256 k]

// kSO1 LDS layout (bytes): 63232 -> 2 blocks/CU
#define SO_FT   0        // ftF [64][264] u16 = 33792
#define SO_CK   33792    // clsK [160][72] u16 = 23040; E [64][168] u16 = 21504 aliases
#define SO_ROWM 56832    // [160][4] f32 = 2560
#define SO_ROWS 59392    // [160][4] f32 = 2560
#define SO_PMX  61952    // [2][64] f32 = 512
#define SO_PZS  62464    // [2][64] f32 = 512
#define SO_RZ   62976    // [64] f32 = 256
#define SO_LDS  63232

// kOut0 LDS (bytes): Ep 23040 + fN-half 18432 = 41472 -> 3 blocks/CU
#define O0_LDS  (NPAD*EP_STRIDE*2 + 128*FN_STRIDE*2)

// workspace offsets (bytes)
#define WS_CLSF  0          // [8][160][256] f16
#define WS_CLSWT 655360     // [8][256][160] f16
#define WS_MG    2359296    // [8][160] f32
#define WS_RZ    2364416    // [8][160] f32
#define WS_WCF   2369536    // [256][256] f16
#define WS_COMBT 2500608    // [8][160][256] f16
#define WS_ROWP  3155968    // [8][256][160][2] f32 (part aliases after kComb)
#define WS_PART  3155968    // [8][32][256][160] f16 (written later by kOut0)
#define WS_S     24127488   // [8][160][16384] f16

__device__ __forceinline__ u16 f2h(float f){ return __builtin_bit_cast(u16, (_Float16)f); }
__device__ __forceinline__ float h2f(u16 h){ return (float)__builtin_bit_cast(_Float16, h); }
__device__ __forceinline__ f16x2 shfl_h2(f16x2 v, int m){
  int x = __builtin_bit_cast(int, v);
  x = __shfl_xor(x, m);
  return __builtin_bit_cast(f16x2, x);
}

// ---------------- k0: cls -> f16 + clsWT = (cls @ Wf^T)^T f16; tail blocks: Wc -> f16
__global__ __launch_bounds__(256) void k0(const float* __restrict__ cls, const float* __restrict__ Wf,
                                          const float* __restrict__ Wc,
                                          u16* __restrict__ clsF, u16* __restrict__ clsWT,
                                          u16* __restrict__ WcF){
  int t = threadIdx.x;
  if (blockIdx.x >= 8*NPAD){
    int i = ((blockIdx.x - 8*NPAD)*256 + t)*4;
    f32x4 v = *(const f32x4*)&Wc[i];
    u16x4 o = {f2h(v[0]), f2h(v[1]), f2h(v[2]), f2h(v[3])};
    *(u16x4*)&WcF[i] = o;
    return;
  }
  int b = blockIdx.x / NPAD, n = blockIdx.x % NPAD;
  __shared__ float row[256];
  int bn = b*NPAD + n;
  if (n < NCLS){
    float v = cls[(b*NCLS + n)*CDIM + t];
    clsF[bn*CDIM + t] = f2h(v);
    row[t] = v;
    __syncthreads();
    float acc = 0.f;
    const float* wr = Wf + t*CDIM;
    #pragma unroll 4
    for (int c = 0; c < 256; c += 4){
      acc += row[c]*wr[c] + row[c+1]*wr[c+1] + row[c+2]*wr[c+2] + row[c+3]*wr[c+3];
    }
    clsWT[(b*CDIM + t)*NPAD + n] = f2h(acc);
  } else {
    clsF[bn*CDIM + t] = 0;
    clsWT[(b*CDIM + t)*NPAD + n] = 0;
  }
}

// ---------------- kSO1 v4: = v3 with packed-f16 row-stat butterflies (80 vs 160 bpermutes)
__global__ __launch_bounds__(512) void kSO1(const float* __restrict__ feat,
                                            const u16* __restrict__ clsF,
                                            const u16* __restrict__ clsWT,
                                            u16* __restrict__ Sg, float* __restrict__ rowP,
                                            float* __restrict__ out1){
  extern __shared__ char sm[];
  u16*  ftF  = (u16*)(sm + SO_FT);
  u16*  clsK = (u16*)(sm + SO_CK);
  u16*  E    = (u16*)(sm + SO_CK);     // alias: clsK dead after S-GEMM
  float* rowM = (float*)(sm + SO_ROWM);
  float* rowS = (float*)(sm + SO_ROWS);
  float* pmx  = (float*)(sm + SO_PMX);
  float* pzs  = (float*)(sm + SO_PZS);
  float* rzL  = (float*)(sm + SO_RZ);

  int b = blockIdx.x & 7, tl = blockIdx.x >> 3, t = threadIdx.x;
  int p0 = tl*64;
  const float* featG = feat + (size_t)b*CDIM*HW;
  const u16* clsB  = clsF  + b*NPAD*CDIM;
  const u16* clsWB = clsWT + b*CDIM*NPAD;
  u16* Sb = Sg + (size_t)b*NPAD*HW;

  int lane = t & 63, wv = t >> 6;
  int l15 = lane & 15, lk = (lane >> 4) & 3;
  int nh = wv >> 2, pq = wv & 3;
  int nbase = nh*80;
  int col = pq*16 + l15;
  int cstrip = wv*32;

  // ---- stage ftF [64px][256c] f32->f16 (once)
  {
    int p = t & 63, cg = t >> 6;
    #pragma unroll
    for (int i = 0; i < 8; ++i){
      int c0 = (i*8 + cg)*4;
      const float* g0 = featG + (size_t)c0*HW + p0 + p;
      float v0 = g0[0], v1 = g0[HW], v2 = g0[2*HW], v3 = g0[3*HW];
      u16x4 hv = {f2h(v0), f2h(v1), f2h(v2), f2h(v3)};
      *(u16x4*)&ftF[p*FT_STRIDE + c0] = hv;
    }
  }
  // ---- S-GEMM: K-loop, cls chunk staged to LDS (coalesced, parallel)
  f32x4 acc[5];
  #pragma unroll
  for (int f = 0; f < 5; ++f) acc[f] = (f32x4){0.f,0.f,0.f,0.f};
  for (int kc = 0; kc < 4; ++kc){
    #pragma unroll
    for (int it = 0; it < 3; ++it){
      int idx = it*512 + t;
      if (idx < 1280){
        int n = idx >> 3, s8 = idx & 7;
        u16x8 v = *(const u16x8*)&clsB[n*CDIM + kc*64 + s8*8];
        *(u16x8*)&clsK[n*KC_STRIDE + s8*8] = v;
      }
    }
    __syncthreads();   // clsK (and on kc=0, ftF) ready
    #pragma unroll
    for (int kb2 = 0; kb2 < 2; ++kb2){
      int kol = kb2*32 + lk*8;
      f16x8 bh = *(const f16x8*)&ftF[(pq*16 + l15)*FT_STRIDE + kc*64 + kol];
      #pragma unroll
      for (int f = 0; f < 5; ++f){
        f16x8 ah = *(const f16x8*)&clsK[(nbase + f*16 + l15)*KC_STRIDE + kol];
        acc[f] = MFMA16F(ah, bh, acc[f], 0, 0, 0);
      }
    }
    __syncthreads();   // clsK reads done before next-stage overwrite
  }
  // ---- preload clsWT fragments early (latency hides under stats phases)
  f16x8 aw0[5], aw1[5];
  #pragma unroll
  for (int kb = 0; kb < 5; ++kb){
    aw0[kb] = *(const f16x8*)&clsWB[(cstrip + l15)*NPAD + kb*32 + lk*8];
    aw1[kb] = *(const f16x8*)&clsWB[(cstrip + 16 + l15)*NPAD + kb*32 + lk*8];
  }
  #pragma unroll
  for (int kb = 0; kb < 5; ++kb){
    asm volatile("" :: "v"(aw0[kb]), "v"(aw1[kb]));
  }
  // ---- write S to global (for kOut0)
  #pragma unroll
  for (int f = 0; f < 5; ++f){
    #pragma unroll
    for (int r = 0; r < 4; ++r){
      int n = nbase + f*16 + 4*lk + r;
      Sb[(size_t)n*HW + p0 + col] = f2h(acc[f][r]);
    }
  }
  // ---- row (cls) stats: packed-f16 butterflies over this wave's 16 cols
  #pragma unroll
  for (int f = 0; f < 5; ++f){
    #pragma unroll
    for (int rp = 0; rp < 2; ++rp){
      float v0 = acc[f][rp*2], v1 = acc[f][rp*2 + 1];
      f16x2 pm_ = {(_Float16)v0, (_Float16)v1};
      pm_ = __builtin_elementwise_max(pm_, shfl_h2(pm_, 1));
      pm_ = __builtin_elementwise_max(pm_, shfl_h2(pm_, 2));
      pm_ = __builtin_elementwise_max(pm_, shfl_h2(pm_, 4));
      pm_ = __builtin_elementwise_max(pm_, shfl_h2(pm_, 8));
      float m0 = (float)pm_[0], m1 = (float)pm_[1];
      f16x2 ps_ = {(_Float16)__expf(v0 - m0), (_Float16)__expf(v1 - m1)};
      ps_ = ps_ + shfl_h2(ps_, 1);
      ps_ = ps_ + shfl_h2(ps_, 2);
      ps_ = ps_ + shfl_h2(ps_, 4);
      ps_ = ps_ + shfl_h2(ps_, 8);
      if (l15 == f){
        int n0 = nbase + f*16 + 4*lk + rp*2;
        rowM[n0*4 + pq]       = m0;
        rowM[(n0 + 1)*4 + pq] = m1;
        rowS[n0*4 + pq]       = (float)ps_[0];
        rowS[(n0 + 1)*4 + pq] = (float)ps_[1];
      }
    }
  }
  // ---- pixel (pos) max: in-lane over 20 vals + shfl over lk -> pmx[nh][col]
  {
    float pmax = -3.0e38f;
    #pragma unroll
    for (int f = 0; f < 5; ++f)
      #pragma unroll
      for (int r = 0; r < 4; ++r){
        int n = nbase + 16*f + 4*lk + r;
        if (n < NCLS) pmax = fmaxf(pmax, acc[f][r]);
      }
    pmax = fmaxf(pmax, __shfl_xor(pmax, 16));
    pmax = fmaxf(pmax, __shfl_xor(pmax, 32));
    if (lk == 0) pmx[nh*64 + col] = pmax;
  }
  __syncthreads();   // pmx + rowM/rowS ready; E region free
  // ---- combine row stats -> rowP (t<160)
  if (t < NPAD){
    float rm0 = rowM[t*4+0], rm1 = rowM[t*4+1], rm2 = rowM[t*4+2], rm3 = rowM[t*4+3];
    float msub = fmaxf(fmaxf(rm0, rm1), fmaxf(rm2, rm3));
    float l = rowS[t*4+0]*__expf(rm0 - msub) + rowS[t*4+1]*__expf(rm1 - msub)
            + rowS[t*4+2]*__expf(rm2 - msub) + rowS[t*4+3]*__expf(rm3 - msub);
    float* rp = rowP + ((size_t)(b*256 + tl)*NPAD + t)*2;
    rp[0] = msub;
    rp[1] = l;
  }
  // ---- exp in-register, write E^T (already exponentiated), z-reduce -> pzs
  {
    float mp_ = fmaxf(pmx[col], pmx[64 + col]);
    float s = 0.f;
    #pragma unroll
    for (int f = 0; f < 5; ++f){
      u16x4 ev;
      #pragma unroll
      for (int r = 0; r < 4; ++r){
        int n = nbase + 16*f + 4*lk + r;
        float e = (n < NCLS) ? __expf(acc[f][r] - mp_) : 0.f;
        s += e;
        ev[r] = f2h(e);
      }
      *(u16x4*)&E[col*W_STRIDE + nbase + 16*f + 4*lk] = ev;
    }
    s += __shfl_xor(s, 16);
    s += __shfl_xor(s, 32);
    if (lk == 0) pzs[nh*64 + col] = s;
  }
  __syncthreads();   // E(exp) + pzs ready
  // ---- rz (t<64) concurrent with out1-GEMM
  if (t < 64) rzL[t] = 1.0f / (pzs[t] + pzs[64 + t]);
  f32x4 accO[2][4];
  #pragma unroll
  for (int cf = 0; cf < 2; ++cf)
    #pragma unroll
    for (int pf = 0; pf < 4; ++pf) accO[cf][pf] = (f32x4){0.f,0.f,0.f,0.f};
  #pragma unroll
  for (int kb = 0; kb < 5; ++kb){
    int ko = kb*32 + lk*8;
    #pragma unroll
    for (int pf = 0; pf < 4; ++pf){
      f16x8 bb = *(const f16x8*)&E[(pf*16 + l15)*W_STRIDE + ko];
      accO[0][pf] = MFMA16F(aw0[kb], bb, accO[0][pf], 0, 0, 0);
      accO[1][pf] = MFMA16F(aw1[kb], bb, accO[1][pf], 0, 0, 0);
    }
  }
  __syncthreads();   // rzL visible
  // ---- epilogue: scale by 1/Z, add f16 feat residual from ftF (still resident)
  #pragma unroll
  for (int cf = 0; cf < 2; ++cf){
    #pragma unroll
    for (int r = 0; r < 4; ++r){
      int c = cstrip + cf*16 + lk*4 + r;
      float* ob = out1 + (size_t)(b*CDIM + c)*HW + p0;
      #pragma unroll
      for (int pf = 0; pf < 4; ++pf){
        int pp = pf*16 + l15;
        ob[pp] = accO[cf][pf][r]*rzL[pp] + h2f(ftF[pp*FT_STRIDE + c]);
      }
    }
  }
}

// ---------------- kComb: reduce 256 tile row-partials -> m_g, rZ (2-level)
__global__ __launch_bounds__(256) void kComb(const float* __restrict__ rowP,
                                             float* __restrict__ mg, float* __restrict__ rz){
  int b = blockIdx.x / 10, nb = blockIdx.x % 10, t = threadIdx.x;
  int sg = t >> 4, j = t & 15;
  int n = nb*16 + j;
  __shared__ float pm[16][17], pl[16][17];
  float m = -3.0e38f, l = 0.f;
  for (int i = 0; i < 16; ++i){
    int s = sg*16 + i;
    const float* rp = rowP + ((size_t)(b*256 + s)*NPAD + n)*2;
    float ms = rp[0], ls = rp[1];
    float mn = fmaxf(m, ms);
    l = l*__expf(m - mn) + ls*__expf(ms - mn);
    m = mn;
  }
  pm[sg][j] = m;
  pl[sg][j] = l;
  __syncthreads();
  if (sg == 0){
    float M = pm[0][j], L = pl[0][j];
    #pragma unroll
    for (int k = 1; k < 16; ++k){
      float ms = pm[k][j], ls = pl[k][j];
      float mn = fmaxf(M, ms);
      L = L*__expf(M - mn) + ls*__expf(ms - mn);
      M = mn;
    }
    mg[b*NPAD + n] = M;
    rz[b*NPAD + n] = 1.0f / L;
  }
}

// ---------------- kOut0 v2: c-split (512 blocks, 3/CU): part[c-half][n] over 512 px
__global__ __launch_bounds__(512) void kOut0(const u16* __restrict__ Sg, const float* __restrict__ feat,
                                             const float* __restrict__ mg, u16* __restrict__ part){
  extern __shared__ char sm[];
  u16* Ep = (u16*)sm;                        // [NPAD][EP_STRIDE]
  u16* fN = (u16*)(sm + NPAD*EP_STRIDE*2);   // [128][FN_STRIDE]
  int b = blockIdx.x & 7, pr = (blockIdx.x >> 3) & 31, ch = (blockIdx.x >> 8) & 1;
  int t = threadIdx.x;
  const u16* Sb = Sg + (size_t)b*NPAD*HW;
  const float* featB = feat + (size_t)b*CDIM*HW;
  const float* mgB = mg + b*NPAD;
  int lane = t & 63, wv = t >> 6;
  int l15 = lane & 15, lk = (lane >> 4) & 3;
  int cstrip = wv*16;
  int rr = t >> 3, px8 = (t & 7)*8;
  f32x4 acc[10];
  #pragma unroll
  for (int nf = 0; nf < 10; ++nf) acc[nf] = (f32x4){0.f,0.f,0.f,0.f};
  for (int ck = 0; ck < 8; ++ck){
    int p0 = pr*512 + ck*64;
    #pragma unroll
    for (int ps = 0; ps < 3; ++ps){
      int rowi = ps*64 + rr;
      if (rowi < NPAD){
        u16x8 v = *(const u16x8*)&Sb[(size_t)rowi*HW + p0 + px8];
        float m = mgB[rowi];
        u16x8 o;
        #pragma unroll
        for (int j = 0; j < 8; ++j) o[j] = f2h(__expf(h2f(v[j]) - m));
        *(u16x8*)&Ep[rowi*EP_STRIDE + px8] = o;
      }
    }
    #pragma unroll
    for (int ps = 0; ps < 2; ++ps){
      int cl = ps*64 + rr;
      const float* g = featB + (size_t)(ch*128 + cl)*HW + p0 + px8;
      f32x4 v0 = *(const f32x4*)&g[0];
      f32x4 v1 = *(const f32x4*)&g[4];
      u16x8 o = {f2h(v0[0]), f2h(v0[1]), f2h(v0[2]), f2h(v0[3]),
                 f2h(v1[0]), f2h(v1[1]), f2h(v1[2]), f2h(v1[3])};
      *(u16x8*)&fN[cl*FN_STRIDE + px8] = o;
    }
    __syncthreads();
    #pragma unroll
    for (int kb = 0; kb < 2; ++kb){
      int ko = kb*32 + lk*8;
      f16x8 a0 = *(const f16x8*)&fN[(cstrip + l15)*FN_STRIDE + ko];
      #pragma unroll
      for (int nf = 0; nf < 10; ++nf){
        f16x8 bb = *(const f16x8*)&Ep[(nf*16 + l15)*EP_STRIDE + ko];
        acc[nf] = MFMA16F(a0, bb, acc[nf], 0, 0, 0);
      }
    }
    __syncthreads();
  }
  #pragma unroll
  for (int nf = 0; nf < 10; ++nf){
    #pragma unroll
    for (int r = 0; r < 4; ++r){
      int c = ch*128 + cstrip + lk*4 + r;
      int n = nf*16 + l15;
      part[((size_t)(b*32 + pr)*CDIM + c)*NPAD + n] = f2h(acc[nf][r]);
    }
  }
}

// ---------------- k4a: streaming reduce of part over 32 chunks, fold rZ -> combT[b][n][c] f16
__global__ __launch_bounds__(256) void k4a(const u16* __restrict__ part, const float* __restrict__ rz,
                                           u16* __restrict__ combT){
  int b = blockIdx.x / 20, sub = blockIdx.x % 20, t = threadIdx.x;
  int idx8 = (sub*256 + t)*8;
  int c = idx8 / NPAD, n0 = idx8 % NPAD;
  const u16* base = part + (size_t)(b*32)*CDIM*NPAD + idx8;
  float a[8];
  #pragma unroll
  for (int j = 0; j < 8; ++j) a[j] = 0.f;
  for (int s = 0; s < 32; ++s){
    u16x8 v = *(const u16x8*)&base[(size_t)s*CDIM*NPAD];
    #pragma unroll
    for (int j = 0; j < 8; ++j) a[j] += h2f(v[j]);
  }
  const float* rzB = rz + b*NPAD + n0;
  #pragma unroll
  for (int j = 0; j < 8; ++j){
    combT[((size_t)(b*NPAD) + n0 + j)*CDIM + c] = f2h(a[j] * rzB[j]);
  }
}

// ---------------- k4b: out0[n][c] = cls + combT[n][:] @ WcF[c][:]  (MFMA, 80 n-rows/block)
__global__ __launch_bounds__(512) void k4b(const u16* __restrict__ combT, const u16* __restrict__ WcF,
                                           const float* __restrict__ cls, float* __restrict__ out0){
  extern __shared__ char sm[];
  u16* A = (u16*)sm;   // [80][CT_STRIDE]
  int b = blockIdx.x >> 1, nb = blockIdx.x & 1, t = threadIdx.x;
  const u16* cb = combT + (size_t)(b*NPAD + nb*80)*CDIM;
  #pragma unroll
  for (int it = 0; it < 10; ++it){
    int idx8 = (it*512 + t)*8;
    if (idx8 < 80*256){
      int row = idx8 >> 8, k0 = idx8 & 255;
      u16x8 v = *(const u16x8*)&cb[idx8];
      *(u16x8*)&A[row*CT_STRIDE + k0] = v;
    }
  }
  __syncthreads();
  int lane = t & 63, wv = t >> 6;
  int l15 = lane & 15, lk = (lane >> 4) & 3;
  int cstrip = wv*32;
  f32x4 acc[5][2];
  #pragma unroll
  for (int f = 0; f < 5; ++f)
    #pragma unroll
    for (int ct = 0; ct < 2; ++ct) acc[f][ct] = (f32x4){0.f,0.f,0.f,0.f};
  #pragma unroll
  for (int kb = 0; kb < 8; ++kb){
    int ko = kb*32 + lk*8;
    f16x8 b0 = *(const f16x8*)&WcF[(cstrip + l15)*CDIM + ko];
    f16x8 b1 = *(const f16x8*)&WcF[(cstrip + 16 + l15)*CDIM + ko];
    #pragma unroll
    for (int f = 0; f < 5; ++f){
      f16x8 af = *(const f16x8*)&A[(f*16 + l15)*CT_STRIDE + ko];
      acc[f][0] = MFMA16F(af, b0, acc[f][0], 0, 0, 0);
      acc[f][1] = MFMA16F(af, b1, acc[f][1], 0, 0, 0);
    }
  }
  #pragma unroll
  for (int f = 0; f < 5; ++f){
    #pragma unroll
    for (int r = 0; r < 4; ++r){
      int n = nb*80 + f*16 + lk*4 + r;
      if (n < NCLS){
        #pragma unroll
        for (int ct = 0; ct < 2; ++ct){
          int c = cstrip + ct*16 + l15;
          out0[(size_t)(b*NCLS + n)*CDIM + c] = cls[(size_t)(b*NCLS + n)*CDIM + c] + acc[f][ct][r];
        }
      }
    }
  }
}

extern "C" void kernel_launch(void* const* d_in, const int* in_sizes, int n_in,
                              void* d_out, int out_size, void* d_ws, size_t ws_size,
                              hipStream_t stream){
  (void)in_sizes; (void)n_in; (void)out_size; (void)ws_size;
  const float* cls  = (const float*)d_in[0];   // [8][150][256]
  const float* feat = (const float*)d_in[1];   // [8][256][16384]
  const float* Wc   = (const float*)d_in[2];   // [256][256]
  const float* Wf   = (const float*)d_in[3];   // [256][256]
  float* out0 = (float*)d_out;                 // [8][150][256]
  float* out1 = out0 + 8*NCLS*CDIM;            // [8][256][16384]
  char* ws = (char*)d_ws;
  u16*   clsF   = (u16*)(ws + WS_CLSF);
  u16*   clsWT  = (u16*)(ws + WS_CLSWT);
  float* mgv    = (float*)(ws + WS_MG);
  float* rzv    = (float*)(ws + WS_RZ);
  u16*   WcFv   = (u16*)(ws + WS_WCF);
  u16*   combTv = (u16*)(ws + WS_COMBT);
  float* rowPv  = (float*)(ws + WS_ROWP);
  u16*   partv  = (u16*)(ws + WS_PART);
  u16*   Sgp    = (u16*)(ws + WS_S);

  (void)hipFuncSetAttribute((const void*)kSO1, hipFuncAttributeMaxDynamicSharedMemorySize, SO_LDS);

  k0   <<<8*NPAD + 64, 256, 0, stream>>>(cls, Wf, Wc, clsF, clsWT, WcFv);
  kSO1 <<<2048, 512, SO_LDS, stream>>>(feat, clsF, clsWT, Sgp, rowPv, out1);
  kComb<<<80, 256, 0, stream>>>(rowPv, mgv, rzv);
  kOut0<<<512, 512, O0_LDS, stream>>>(Sgp, feat, mgv, partv);
  k4a  <<<160, 256, 0, stream>>>(partv, rzv, combTv);
  k4b  <<<16, 512, 80*CT_STRIDE*2, stream>>>(combTv, WcFv, cls, out0);
}

// Round 16
// 192.284 us; speedup vs baseline: 1.1987x; 1.0154x over previous
//
#include <hip/hip_runtime.h>

typedef unsigned short u16;
typedef __attribute__((ext_vector_type(8))) _Float16 f16x8;
typedef __attribute__((ext_vector_type(2))) _Float16 f16x2;
typedef __attribute__((ext_vector_type(4))) float f32x4;
typedef __attribute__((ext_vector_type(4))) unsigned short u16x4;
typedef __attribute__((ext_vector_type(8))) unsigned short u16x8;

#define MFMA16F __builtin_amdgcn_mfma_f32_16x16x32_f16

#define HW   16384
#define NCLS 150
#define NPAD 160
#define CDIM 256

// LDS strides (shorts)
#define FT_STRIDE 264   // ftF [64 px][256 c]
#define CL_STRIDE 264   // clsL [160 n][256 c] (resident)
#define FN_STRIDE 72    // featN [c][64 px]
#define EP_STRIDE 72    // E'    [160 n][64 px]
#define W_STRIDE  168   // E [64 px][160 n]; clsWT rows
#define CT_STRIDE 264   // combT tile [80 n][256 k]

// kSO1 v5 LDS layout (bytes): 146176 -> 1 block/CU (by design; cls resident)
#define SO_CL   0        // clsL [160][264] u16 = 84480
#define SO_FT   84480    // ftF [64][264] u16 = 33792
#define SO_E    118272   // E [64][168] u16 = 21504
#define SO_ROWM 139776   // [160][4] f32 = 2560
#define SO_ROWS 142336   // [160][4] f32 = 2560
#define SO_PMX  144896   // [2][64] f32 = 512
#define SO_PZS  145408   // [2][64] f32 = 512
#define SO_RZ   145920   // [64] f32 = 256
#define SO_LDS  146176

// kOut0 LDS (bytes): Ep 23040 + fN-half 18432 = 41472 -> 3 blocks/CU
#define O0_LDS  (NPAD*EP_STRIDE*2 + 128*FN_STRIDE*2)

// workspace offsets (bytes)
#define WS_CLSF  0          // [8][160][256] f16
#define WS_CLSWT 655360     // [8][256][160] f16
#define WS_MG    2359296    // [8][160] f32
#define WS_RZ    2364416    // [8][160] f32
#define WS_WCF   2369536    // [256][256] f16
#define WS_COMBT 2500608    // [8][160][256] f16
#define WS_ROWP  3155968    // [8][256][160][2] f32 (part aliases after kComb)
#define WS_PART  3155968    // [8][32][256][160] f16 (written later by kOut0)
#define WS_S     24127488   // [8][160][16384] f16

__device__ __forceinline__ u16 f2h(float f){ return __builtin_bit_cast(u16, (_Float16)f); }
__device__ __forceinline__ float h2f(u16 h){ return (float)__builtin_bit_cast(_Float16, h); }
__device__ __forceinline__ f16x2 shfl_h2(f16x2 v, int m){
  int x = __builtin_bit_cast(int, v);
  x = __shfl_xor(x, m);
  return __builtin_bit_cast(f16x2, x);
}

// ---------------- k0: cls -> f16 + clsWT = (cls @ Wf^T)^T f16; tail blocks: Wc -> f16
__global__ __launch_bounds__(256) void k0(const float* __restrict__ cls, const float* __restrict__ Wf,
                                          const float* __restrict__ Wc,
                                          u16* __restrict__ clsF, u16* __restrict__ clsWT,
                                          u16* __restrict__ WcF){
  int t = threadIdx.x;
  if (blockIdx.x >= 8*NPAD){
    int i = ((blockIdx.x - 8*NPAD)*256 + t)*4;
    f32x4 v = *(const f32x4*)&Wc[i];
    u16x4 o = {f2h(v[0]), f2h(v[1]), f2h(v[2]), f2h(v[3])};
    *(u16x4*)&WcF[i] = o;
    return;
  }
  int b = blockIdx.x / NPAD, n = blockIdx.x % NPAD;
  __shared__ float row[256];
  int bn = b*NPAD + n;
  if (n < NCLS){
    float v = cls[(b*NCLS + n)*CDIM + t];
    clsF[bn*CDIM + t] = f2h(v);
    row[t] = v;
    __syncthreads();
    float acc = 0.f;
    const float* wr = Wf + t*CDIM;
    #pragma unroll 4
    for (int c = 0; c < 256; c += 4){
      acc += row[c]*wr[c] + row[c+1]*wr[c+1] + row[c+2]*wr[c+2] + row[c+3]*wr[c+3];
    }
    clsWT[(b*CDIM + t)*NPAD + n] = f2h(acc);
  } else {
    clsF[bn*CDIM + t] = 0;
    clsWT[(b*CDIM + t)*NPAD + n] = 0;
  }
}

// ---------------- kSO1 v5: resident clsL (1 blk/CU), 4 tiles/block, feat prefetch-to-regs,
//                  5 barriers/tile (was 11).
__global__ __launch_bounds__(512) void kSO1(const float* __restrict__ feat,
                                            const u16* __restrict__ clsF,
                                            const u16* __restrict__ clsWT,
                                            u16* __restrict__ Sg, float* __restrict__ rowP,
                                            float* __restrict__ out1){
  extern __shared__ char sm[];
  u16*  clsL = (u16*)(sm + SO_CL);
  u16*  ftF  = (u16*)(sm + SO_FT);
  u16*  E    = (u16*)(sm + SO_E);
  float* rowM = (float*)(sm + SO_ROWM);
  float* rowS = (float*)(sm + SO_ROWS);
  float* pmx  = (float*)(sm + SO_PMX);
  float* pzs  = (float*)(sm + SO_PZS);
  float* rzL  = (float*)(sm + SO_RZ);

  int b = blockIdx.x & 7, ch = blockIdx.x >> 3, t = threadIdx.x;
  const float* featG = feat + (size_t)b*CDIM*HW;
  const u16* clsB  = clsF  + b*NPAD*CDIM;
  const u16* clsWB = clsWT + b*CDIM*NPAD;
  u16* Sb = Sg + (size_t)b*NPAD*HW;

  int lane = t & 63, wv = t >> 6;
  int l15 = lane & 15, lk = (lane >> 4) & 3;
  int nh = wv >> 2, pq = wv & 3;
  int nbase = nh*80;
  int col = pq*16 + l15;
  int cstrip = wv*32;
  int p = t & 63, cg = t >> 6;

  // ---- prologue: stage clsL (once), preload clsWT frags (per-wave const), load tile-0 feat
  #pragma unroll
  for (int it = 0; it < 10; ++it){
    int idx8 = (it*512 + t)*8;
    int n = idx8 >> 8, c = idx8 & 255;
    u16x8 v = *(const u16x8*)&clsB[idx8];
    *(u16x8*)&clsL[n*CL_STRIDE + c] = v;
  }
  f16x8 aw0[5], aw1[5];
  #pragma unroll
  for (int kb = 0; kb < 5; ++kb){
    aw0[kb] = *(const f16x8*)&clsWB[(cstrip + l15)*NPAD + kb*32 + lk*8];
    aw1[kb] = *(const f16x8*)&clsWB[(cstrip + 16 + l15)*NPAD + kb*32 + lk*8];
  }
  #pragma unroll
  for (int kb = 0; kb < 5; ++kb){
    asm volatile("" :: "v"(aw0[kb]), "v"(aw1[kb]));
  }
  f32x4 pf[8];
  {
    int p00 = ch*256;
    #pragma unroll
    for (int i = 0; i < 8; ++i){
      int c0 = (i*8 + cg)*4;
      const float* g0 = featG + (size_t)c0*HW + p00 + p;
      pf[i][0] = g0[0]; pf[i][1] = g0[HW]; pf[i][2] = g0[2*HW]; pf[i][3] = g0[3*HW];
    }
  }

  for (int tl = 0; tl < 4; ++tl){
    int p0 = ch*256 + tl*64;
    __syncthreads();   // B_a: prior tile's ftF/E readers done (iter 0: clsL writes done)
    // ---- ds_write ftF from prefetched regs; issue next tile's loads
    #pragma unroll
    for (int i = 0; i < 8; ++i){
      int c0 = (i*8 + cg)*4;
      u16x4 hv = {f2h(pf[i][0]), f2h(pf[i][1]), f2h(pf[i][2]), f2h(pf[i][3])};
      *(u16x4*)&ftF[p*FT_STRIDE + c0] = hv;
    }
    if (tl < 3){
      int p0n = p0 + 64;
      #pragma unroll
      for (int i = 0; i < 8; ++i){
        int c0 = (i*8 + cg)*4;
        const float* g0 = featG + (size_t)c0*HW + p0n + p;
        pf[i][0] = g0[0]; pf[i][1] = g0[HW]; pf[i][2] = g0[2*HW]; pf[i][3] = g0[3*HW];
      }
    }
    __syncthreads();   // B_b: ftF ready
    // ---- S-GEMM: straight 40 MFMA, clsL resident (no staging barriers)
    f32x4 acc[5];
    #pragma unroll
    for (int f = 0; f < 5; ++f) acc[f] = (f32x4){0.f,0.f,0.f,0.f};
    #pragma unroll
    for (int kb = 0; kb < 8; ++kb){
      int ko = kb*32 + lk*8;
      f16x8 bh = *(const f16x8*)&ftF[(pq*16 + l15)*FT_STRIDE + ko];
      #pragma unroll
      for (int f = 0; f < 5; ++f){
        f16x8 ah = *(const f16x8*)&clsL[(nbase + f*16 + l15)*CL_STRIDE + ko];
        acc[f] = MFMA16F(ah, bh, acc[f], 0, 0, 0);
      }
    }
    // ---- write S to global (for kOut0)
    #pragma unroll
    for (int f = 0; f < 5; ++f){
      #pragma unroll
      for (int r = 0; r < 4; ++r){
        int n = nbase + f*16 + 4*lk + r;
        Sb[(size_t)n*HW + p0 + col] = f2h(acc[f][r]);
      }
    }
    // ---- row (cls) stats: packed-f16 butterflies over this wave's 16 cols
    #pragma unroll
    for (int f = 0; f < 5; ++f){
      #pragma unroll
      for (int rp = 0; rp < 2; ++rp){
        float v0 = acc[f][rp*2], v1 = acc[f][rp*2 + 1];
        f16x2 pm_ = {(_Float16)v0, (_Float16)v1};
        pm_ = __builtin_elementwise_max(pm_, shfl_h2(pm_, 1));
        pm_ = __builtin_elementwise_max(pm_, shfl_h2(pm_, 2));
        pm_ = __builtin_elementwise_max(pm_, shfl_h2(pm_, 4));
        pm_ = __builtin_elementwise_max(pm_, shfl_h2(pm_, 8));
        float m0 = (float)pm_[0], m1 = (float)pm_[1];
        f16x2 ps_ = {(_Float16)__expf(v0 - m0), (_Float16)__expf(v1 - m1)};
        ps_ = ps_ + shfl_h2(ps_, 1);
        ps_ = ps_ + shfl_h2(ps_, 2);
        ps_ = ps_ + shfl_h2(ps_, 4);
        ps_ = ps_ + shfl_h2(ps_, 8);
        if (l15 == f){
          int n0 = nbase + f*16 + 4*lk + rp*2;
          rowM[n0*4 + pq]       = m0;
          rowM[(n0 + 1)*4 + pq] = m1;
          rowS[n0*4 + pq]       = (float)ps_[0];
          rowS[(n0 + 1)*4 + pq] = (float)ps_[1];
        }
      }
    }
    // ---- pixel (pos) max: in-lane + shfl over lk -> pmx[nh][col]
    {
      float pmax = -3.0e38f;
      #pragma unroll
      for (int f = 0; f < 5; ++f)
        #pragma unroll
        for (int r = 0; r < 4; ++r){
          int n = nbase + 16*f + 4*lk + r;
          if (n < NCLS) pmax = fmaxf(pmax, acc[f][r]);
        }
      pmax = fmaxf(pmax, __shfl_xor(pmax, 16));
      pmax = fmaxf(pmax, __shfl_xor(pmax, 32));
      if (lk == 0) pmx[nh*64 + col] = pmax;
    }
    __syncthreads();   // B_c: pmx + rowM/rowS ready
    // ---- combine row stats -> rowP (t<160); global tile index ch*4+tl
    if (t < NPAD){
      float rm0 = rowM[t*4+0], rm1 = rowM[t*4+1], rm2 = rowM[t*4+2], rm3 = rowM[t*4+3];
      float msub = fmaxf(fmaxf(rm0, rm1), fmaxf(rm2, rm3));
      float l = rowS[t*4+0]*__expf(rm0 - msub) + rowS[t*4+1]*__expf(rm1 - msub)
              + rowS[t*4+2]*__expf(rm2 - msub) + rowS[t*4+3]*__expf(rm3 - msub);
      float* rp = rowP + ((size_t)(b*256 + ch*4 + tl)*NPAD + t)*2;
      rp[0] = msub;
      rp[1] = l;
    }
    // ---- exp in-register, write E^T (exponentiated), z-reduce -> pzs
    {
      float mp_ = fmaxf(pmx[col], pmx[64 + col]);
      float s = 0.f;
      #pragma unroll
      for (int f = 0; f < 5; ++f){
        u16x4 ev;
        #pragma unroll
        for (int r = 0; r < 4; ++r){
          int n = nbase + 16*f + 4*lk + r;
          float e = (n < NCLS) ? __expf(acc[f][r] - mp_) : 0.f;
          s += e;
          ev[r] = f2h(e);
        }
        *(u16x4*)&E[col*W_STRIDE + nbase + 16*f + 4*lk] = ev;
      }
      s += __shfl_xor(s, 16);
      s += __shfl_xor(s, 32);
      if (lk == 0) pzs[nh*64 + col] = s;
    }
    __syncthreads();   // B_d: E(exp) + pzs ready
    // ---- rz (t<64) concurrent with out1-GEMM
    if (t < 64) rzL[t] = 1.0f / (pzs[t] + pzs[64 + t]);
    f32x4 accO[2][4];
    #pragma unroll
    for (int cf = 0; cf < 2; ++cf)
      #pragma unroll
      for (int pfi = 0; pfi < 4; ++pfi) accO[cf][pfi] = (f32x4){0.f,0.f,0.f,0.f};
    #pragma unroll
    for (int kb = 0; kb < 5; ++kb){
      int ko = kb*32 + lk*8;
      #pragma unroll
      for (int pfi = 0; pfi < 4; ++pfi){
        f16x8 bb = *(const f16x8*)&E[(pfi*16 + l15)*W_STRIDE + ko];
        accO[0][pfi] = MFMA16F(aw0[kb], bb, accO[0][pfi], 0, 0, 0);
        accO[1][pfi] = MFMA16F(aw1[kb], bb, accO[1][pfi], 0, 0, 0);
      }
    }
    __syncthreads();   // B_e: rzL visible
    // ---- epilogue: scale by 1/Z, add f16 feat residual from ftF
    #pragma unroll
    for (int cf = 0; cf < 2; ++cf){
      #pragma unroll
      for (int r = 0; r < 4; ++r){
        int c = cstrip + cf*16 + lk*4 + r;
        float* ob = out1 + (size_t)(b*CDIM + c)*HW + p0;
        #pragma unroll
        for (int pfi = 0; pfi < 4; ++pfi){
          int pp = pfi*16 + l15;
          ob[pp] = accO[cf][pfi][r]*rzL[pp] + h2f(ftF[pp*FT_STRIDE + c]);
        }
      }
    }
  }
}

// ---------------- kComb: reduce 256 tile row-partials -> m_g, rZ (2-level)
__global__ __launch_bounds__(256) void kComb(const float* __restrict__ rowP,
                                             float* __restrict__ mg, float* __restrict__ rz){
  int b = blockIdx.x / 10, nb = blockIdx.x % 10, t = threadIdx.x;
  int sg = t >> 4, j = t & 15;
  int n = nb*16 + j;
  __shared__ float pm[16][17], pl[16][17];
  float m = -3.0e38f, l = 0.f;
  for (int i = 0; i < 16; ++i){
    int s = sg*16 + i;
    const float* rp = rowP + ((size_t)(b*256 + s)*NPAD + n)*2;
    float ms = rp[0], ls = rp[1];
    float mn = fmaxf(m, ms);
    l = l*__expf(m - mn) + ls*__expf(ms - mn);
    m = mn;
  }
  pm[sg][j] = m;
  pl[sg][j] = l;
  __syncthreads();
  if (sg == 0){
    float M = pm[0][j], L = pl[0][j];
    #pragma unroll
    for (int k = 1; k < 16; ++k){
      float ms = pm[k][j], ls = pl[k][j];
      float mn = fmaxf(M, ms);
      L = L*__expf(M - mn) + ls*__expf(ms - mn);
      M = mn;
    }
    mg[b*NPAD + n] = M;
    rz[b*NPAD + n] = 1.0f / L;
  }
}

// ---------------- kOut0 v2: c-split (512 blocks, 3/CU): part[c-half][n] over 512 px
__global__ __launch_bounds__(512) void kOut0(const u16* __restrict__ Sg, const float* __restrict__ feat,
                                             const float* __restrict__ mg, u16* __restrict__ part){
  extern __shared__ char sm[];
  u16* Ep = (u16*)sm;                        // [NPAD][EP_STRIDE]
  u16* fN = (u16*)(sm + NPAD*EP_STRIDE*2);   // [128][FN_STRIDE]
  int b = blockIdx.x & 7, pr = (blockIdx.x >> 3) & 31, ch = (blockIdx.x >> 8) & 1;
  int t = threadIdx.x;
  const u16* Sb = Sg + (size_t)b*NPAD*HW;
  const float* featB = feat + (size_t)b*CDIM*HW;
  const float* mgB = mg + b*NPAD;
  int lane = t & 63, wv = t >> 6;
  int l15 = lane & 15, lk = (lane >> 4) & 3;
  int cstrip = wv*16;
  int rr = t >> 3, px8 = (t & 7)*8;
  f32x4 acc[10];
  #pragma unroll
  for (int nf = 0; nf < 10; ++nf) acc[nf] = (f32x4){0.f,0.f,0.f,0.f};
  for (int ck = 0; ck < 8; ++ck){
    int p0 = pr*512 + ck*64;
    #pragma unroll
    for (int ps = 0; ps < 3; ++ps){
      int rowi = ps*64 + rr;
      if (rowi < NPAD){
        u16x8 v = *(const u16x8*)&Sb[(size_t)rowi*HW + p0 + px8];
        float m = mgB[rowi];
        u16x8 o;
        #pragma unroll
        for (int j = 0; j < 8; ++j) o[j] = f2h(__expf(h2f(v[j]) - m));
        *(u16x8*)&Ep[rowi*EP_STRIDE + px8] = o;
      }
    }
    #pragma unroll
    for (int ps = 0; ps < 2; ++ps){
      int cl = ps*64 + rr;
      const float* g = featB + (size_t)(ch*128 + cl)*HW + p0 + px8;
      f32x4 v0 = *(const f32x4*)&g[0];
      f32x4 v1 = *(const f32x4*)&g[4];
      u16x8 o = {f2h(v0[0]), f2h(v0[1]), f2h(v0[2]), f2h(v0[3]),
                 f2h(v1[0]), f2h(v1[1]), f2h(v1[2]), f2h(v1[3])};
      *(u16x8*)&fN[cl*FN_STRIDE + px8] = o;
    }
    __syncthreads();
    #pragma unroll
    for (int kb = 0; kb < 2; ++kb){
      int ko = kb*32 + lk*8;
      f16x8 a0 = *(const f16x8*)&fN[(cstrip + l15)*FN_STRIDE + ko];
      #pragma unroll
      for (int nf = 0; nf < 10; ++nf){
        f16x8 bb = *(const f16x8*)&Ep[(nf*16 + l15)*EP_STRIDE + ko];
        acc[nf] = MFMA16F(a0, bb, acc[nf], 0, 0, 0);
      }
    }
    __syncthreads();
  }
  #pragma unroll
  for (int nf = 0; nf < 10; ++nf){
    #pragma unroll
    for (int r = 0; r < 4; ++r){
      int c = ch*128 + cstrip + lk*4 + r;
      int n = nf*16 + l15;
      part[((size_t)(b*32 + pr)*CDIM + c)*NPAD + n] = f2h(acc[nf][r]);
    }
  }
}

// ---------------- k4a: streaming reduce of part over 32 chunks, fold rZ -> combT[b][n][c] f16
__global__ __launch_bounds__(256) void k4a(const u16* __restrict__ part, const float* __restrict__ rz,
                                           u16* __restrict__ combT){
  int b = blockIdx.x / 20, sub = blockIdx.x % 20, t = threadIdx.x;
  int idx8 = (sub*256 + t)*8;
  int c = idx8 / NPAD, n0 = idx8 % NPAD;
  const u16* base = part + (size_t)(b*32)*CDIM*NPAD + idx8;
  float a[8];
  #pragma unroll
  for (int j = 0; j < 8; ++j) a[j] = 0.f;
  for (int s = 0; s < 32; ++s){
    u16x8 v = *(const u16x8*)&base[(size_t)s*CDIM*NPAD];
    #pragma unroll
    for (int j = 0; j < 8; ++j) a[j] += h2f(v[j]);
  }
  const float* rzB = rz + b*NPAD + n0;
  #pragma unroll
  for (int j = 0; j < 8; ++j){
    combT[((size_t)(b*NPAD) + n0 + j)*CDIM + c] = f2h(a[j] * rzB[j]);
  }
}

// ---------------- k4b: out0[n][c] = cls + combT[n][:] @ WcF[c][:]  (MFMA, 80 n-rows/block)
__global__ __launch_bounds__(512) void k4b(const u16* __restrict__ combT, const u16* __restrict__ WcF,
                                           const float* __restrict__ cls, float* __restrict__ out0){
  extern __shared__ char sm[];
  u16* A = (u16*)sm;   // [80][CT_STRIDE]
  int b = blockIdx.x >> 1, nb = blockIdx.x & 1, t = threadIdx.x;
  const u16* cb = combT + (size_t)(b*NPAD + nb*80)*CDIM;
  #pragma unroll
  for (int it = 0; it < 10; ++it){
    int idx8 = (it*512 + t)*8;
    if (idx8 < 80*256){
      int row = idx8 >> 8, k0 = idx8 & 255;
      u16x8 v = *(const u16x8*)&cb[idx8];
      *(u16x8*)&A[row*CT_STRIDE + k0] = v;
    }
  }
  __syncthreads();
  int lane = t & 63, wv = t >> 6;
  int l15 = lane & 15, lk = (lane >> 4) & 3;
  int cstrip = wv*32;
  f32x4 acc[5][2];
  #pragma unroll
  for (int f = 0; f < 5; ++f)
    #pragma unroll
    for (int ct = 0; ct < 2; ++ct) acc[f][ct] = (f32x4){0.f,0.f,0.f,0.f};
  #pragma unroll
  for (int kb = 0; kb < 8; ++kb){
    int ko = kb*32 + lk*8;
    f16x8 b0 = *(const f16x8*)&WcF[(cstrip + l15)*CDIM + ko];
    f16x8 b1 = *(const f16x8*)&WcF[(cstrip + 16 + l15)*CDIM + ko];
    #pragma unroll
    for (int f = 0; f < 5; ++f){
      f16x8 af = *(const f16x8*)&A[(f*16 + l15)*CT_STRIDE + ko];
      acc[f][0] = MFMA16F(af, b0, acc[f][0], 0, 0, 0);
      acc[f][1] = MFMA16F(af, b1, acc[f][1], 0, 0, 0);
    }
  }
  #pragma unroll
  for (int f = 0; f < 5; ++f){
    #pragma unroll
    for (int r = 0; r < 4; ++r){
      int n = nb*80 + f*16 + lk*4 + r;
      if (n < NCLS){
        #pragma unroll
        for (int ct = 0; ct < 2; ++ct){
          int c = cstrip + ct*16 + l15;
          out0[(size_t)(b*NCLS + n)*CDIM + c] = cls[(size_t)(b*NCLS + n)*CDIM + c] + acc[f][ct][r];
        }
      }
    }
  }
}

extern "C" void kernel_launch(void* const* d_in, const int* in_sizes, int n_in,
                              void* d_out, int out_size, void* d_ws, size_t ws_size,
                              hipStream_t stream){
  (void)in_sizes; (void)n_in; (void)out_size; (void)ws_size;
  const float* cls  = (const float*)d_in[0];   // [8][150][256]
  const float* feat = (const float*)d_in[1];   // [8][256][16384]
  const float* Wc   = (const float*)d_in[2];   // [256][256]
  const float* Wf   = (const float*)d_in[3];   // [256][256]
  float* out0 = (float*)d_out;                 // [8][150][256]
  float* out1 = out0 + 8*NCLS*CDIM;            // [8][256][16384]
  char* ws = (char*)d_ws;
  u16*   clsF   = (u16*)(ws + WS_CLSF);
  u16*   clsWT  = (u16*)(ws + WS_CLSWT);
  float* mgv    = (float*)(ws + WS_MG);
  float* rzv    = (float*)(ws + WS_RZ);
  u16*   WcFv   = (u16*)(ws + WS_WCF);
  u16*   combTv = (u16*)(ws + WS_COMBT);
  float* rowPv  = (float*)(ws + WS_ROWP);
  u16*   partv  = (u16*)(ws + WS_PART);
  u16*   Sgp    = (u16*)(ws + WS_S);

  (void)hipFuncSetAttribute((const void*)kSO1, hipFuncAttributeMaxDynamicSharedMemorySize, SO_LDS);

  k0   <<<8*NPAD + 64, 256, 0, stream>>>(cls, Wf, Wc, clsF, clsWT, WcFv);
  kSO1 <<<512, 512, SO_LDS, stream>>>(feat, clsF, clsWT, Sgp, rowPv, out1);
  kComb<<<80, 256, 0, stream>>>(rowPv, mgv, rzv);
  kOut0<<<512, 512, O0_LDS, stream>>>(Sgp, feat, mgv, partv);
  k4a  <<<160, 256, 0, stream>>>(partv, rzv, combTv);
  k4b  <<<16, 512, 80*CT_STRIDE*2, stream>>>(combTv, WcFv, cls, out0);
}

// Round 17
// 191.728 us; speedup vs baseline: 1.2022x; 1.0029x over previous
//
#include <hip/hip_runtime.h>

typedef unsigned short u16;
typedef __attribute__((ext_vector_type(8))) _Float16 f16x8;
typedef __attribute__((ext_vector_type(2))) _Float16 f16x2;
typedef __attribute__((ext_vector_type(4))) float f32x4;
typedef __attribute__((ext_vector_type(4))) unsigned short u16x4;
typedef __attribute__((ext_vector_type(8))) unsigned short u16x8;

#define MFMA16F __builtin_amdgcn_mfma_f32_16x16x32_f16

// barrier that waits LDS ops only — lets global stores / prefetch loads fly across
// (plain __syncthreads drains vmcnt(0): ~60 in-flight stores per tile serialized)
#define BAR_LDS() do{ asm volatile("s_waitcnt lgkmcnt(0)" ::: "memory"); \
                      __builtin_amdgcn_s_barrier(); }while(0)

#define HW   16384
#define NCLS 150
#define NPAD 160
#define CDIM 256

// LDS strides (shorts)
#define FT_STRIDE 264   // ftF [64 px][256 c]
#define CL_STRIDE 264   // clsL [160 n][256 c] (resident)
#define FN_STRIDE 72    // featN [c][64 px]
#define EP_STRIDE 72    // E'    [160 n][64 px]
#define W_STRIDE  168   // E [64 px][160 n]; clsWT rows
#define CT_STRIDE 264   // combT tile [80 n][256 k]

// kSO1 v6 LDS layout (bytes): 146176 -> 1 block/CU (cls resident)
#define SO_CL   0        // clsL [160][264] u16 = 84480
#define SO_FT   84480    // ftF [64][264] u16 = 33792
#define SO_E    118272   // E [64][168] u16 = 21504
#define SO_ROWM 139776   // [160][4] f32 = 2560
#define SO_ROWS 142336   // [160][4] f32 = 2560
#define SO_PMX  144896   // [2][64] f32 = 512
#define SO_PZS  145408   // [2][64] f32 = 512
#define SO_RZ   145920   // [64] f32 = 256
#define SO_LDS  146176

// kOut0 LDS (bytes): Ep 23040 + fN-half 18432 = 41472
#define O0_LDS  (NPAAD_GUARD)
#undef O0_LDS
#define O0_LDS  (NPAD*EP_STRIDE*2 + 128*FN_STRIDE*2)

// workspace offsets (bytes)
#define WS_CLSF  0          // [8][160][256] f16
#define WS_CLSWT 655360     // [8][256][160] f16
#define WS_MG    2359296    // [8][160] f32
#define WS_RZ    2364416    // [8][160] f32
#define WS_WCF   2369536    // [256][256] f16
#define WS_COMBT 2500608    // [8][160][256] f16
#define WS_ROWP  3155968    // [8][256][160][2] f32 (part aliases after kComb)
#define WS_PART  3155968    // [8][32][256][160] f16 (written later by kOut0)
#define WS_S     24127488   // [8][160][16384] f16

__device__ __forceinline__ u16 f2h(float f){ return __builtin_bit_cast(u16, (_Float16)f); }
__device__ __forceinline__ float h2f(u16 h){ return (float)__builtin_bit_cast(_Float16, h); }
__device__ __forceinline__ f16x2 shfl_h2(f16x2 v, int m){
  int x = __builtin_bit_cast(int, v);
  x = __shfl_xor(x, m);
  return __builtin_bit_cast(f16x2, x);
}

// ---------------- k0: cls -> f16 + clsWT = (cls @ Wf^T)^T f16; tail blocks: Wc -> f16
__global__ __launch_bounds__(256) void k0(const float* __restrict__ cls, const float* __restrict__ Wf,
                                          const float* __restrict__ Wc,
                                          u16* __restrict__ clsF, u16* __restrict__ clsWT,
                                          u16* __restrict__ WcF){
  int t = threadIdx.x;
  if (blockIdx.x >= 8*NPAD){
    int i = ((blockIdx.x - 8*NPAD)*256 + t)*4;
    f32x4 v = *(const f32x4*)&Wc[i];
    u16x4 o = {f2h(v[0]), f2h(v[1]), f2h(v[2]), f2h(v[3])};
    *(u16x4*)&WcF[i] = o;
    return;
  }
  int b = blockIdx.x / NPAD, n = blockIdx.x % NPAD;
  __shared__ float row[256];
  int bn = b*NPAD + n;
  if (n < NCLS){
    float v = cls[(b*NCLS + n)*CDIM + t];
    clsF[bn*CDIM + t] = f2h(v);
    row[t] = v;
    __syncthreads();
    float acc = 0.f;
    const float* wr = Wf + t*CDIM;
    #pragma unroll 4
    for (int c = 0; c < 256; c += 4){
      acc += row[c]*wr[c] + row[c+1]*wr[c+1] + row[c+2]*wr[c+2] + row[c+3]*wr[c+3];
    }
    clsWT[(b*CDIM + t)*NPAD + n] = f2h(acc);
  } else {
    clsF[bn*CDIM + t] = 0;
    clsWT[(b*CDIM + t)*NPAD + n] = 0;
  }
}

// ---------------- kSO1 v6: v5 + lgkmcnt-only barriers (stores fly) + setprio on MFMA clusters
__global__ __launch_bounds__(512) void kSO1(const float* __restrict__ feat,
                                            const u16* __restrict__ clsF,
                                            const u16* __restrict__ clsWT,
                                            u16* __restrict__ Sg, float* __restrict__ rowP,
                                            float* __restrict__ out1){
  extern __shared__ char sm[];
  u16*  clsL = (u16*)(sm + SO_CL);
  u16*  ftF  = (u16*)(sm + SO_FT);
  u16*  E    = (u16*)(sm + SO_E);
  float* rowM = (float*)(sm + SO_ROWM);
  float* rowS = (float*)(sm + SO_ROWS);
  float* pmx  = (float*)(sm + SO_PMX);
  float* pzs  = (float*)(sm + SO_PZS);
  float* rzL  = (float*)(sm + SO_RZ);

  int b = blockIdx.x & 7, ch = blockIdx.x >> 3, t = threadIdx.x;
  const float* featG = feat + (size_t)b*CDIM*HW;
  const u16* clsB  = clsF  + b*NPAD*CDIM;
  const u16* clsWB = clsWT + b*CDIM*NPAD;
  u16* Sb = Sg + (size_t)b*NPAD*HW;

  int lane = t & 63, wv = t >> 6;
  int l15 = lane & 15, lk = (lane >> 4) & 3;
  int nh = wv >> 2, pq = wv & 3;
  int nbase = nh*80;
  int col = pq*16 + l15;
  int cstrip = wv*32;
  int p = t & 63, cg = t >> 6;

  // ---- prologue: stage clsL (once), preload clsWT frags, load tile-0 feat
  #pragma unroll
  for (int it = 0; it < 10; ++it){
    int idx8 = (it*512 + t)*8;
    int n = idx8 >> 8, c = idx8 & 255;
    u16x8 v = *(const u16x8*)&clsB[idx8];
    *(u16x8*)&clsL[n*CL_STRIDE + c] = v;
  }
  f16x8 aw0[5], aw1[5];
  #pragma unroll
  for (int kb = 0; kb < 5; ++kb){
    aw0[kb] = *(const f16x8*)&clsWB[(cstrip + l15)*NPAD + kb*32 + lk*8];
    aw1[kb] = *(const f16x8*)&clsWB[(cstrip + 16 + l15)*NPAD + kb*32 + lk*8];
  }
  #pragma unroll
  for (int kb = 0; kb < 5; ++kb){
    asm volatile("" :: "v"(aw0[kb]), "v"(aw1[kb]));
  }
  f32x4 pf[8];
  {
    int p00 = ch*256;
    #pragma unroll
    for (int i = 0; i < 8; ++i){
      int c0 = (i*8 + cg)*4;
      const float* g0 = featG + (size_t)c0*HW + p00 + p;
      pf[i][0] = g0[0]; pf[i][1] = g0[HW]; pf[i][2] = g0[2*HW]; pf[i][3] = g0[3*HW];
    }
  }

  for (int tl = 0; tl < 4; ++tl){
    int p0 = ch*256 + tl*64;
    BAR_LDS();   // B_a: prior tile's LDS readers done (iter0: clsL writes done)
    // ---- ds_write ftF from prefetched regs; issue next tile's loads
    #pragma unroll
    for (int i = 0; i < 8; ++i){
      int c0 = (i*8 + cg)*4;
      u16x4 hv = {f2h(pf[i][0]), f2h(pf[i][1]), f2h(pf[i][2]), f2h(pf[i][3])};
      *(u16x4*)&ftF[p*FT_STRIDE + c0] = hv;
    }
    if (tl < 3){
      int p0n = p0 + 64;
      #pragma unroll
      for (int i = 0; i < 8; ++i){
        int c0 = (i*8 + cg)*4;
        const float* g0 = featG + (size_t)c0*HW + p0n + p;
        pf[i][0] = g0[0]; pf[i][1] = g0[HW]; pf[i][2] = g0[2*HW]; pf[i][3] = g0[3*HW];
      }
    }
    BAR_LDS();   // B_b: ftF ready
    // ---- S-GEMM: straight 40 MFMA, clsL resident
    f32x4 acc[5];
    #pragma unroll
    for (int f = 0; f < 5; ++f) acc[f] = (f32x4){0.f,0.f,0.f,0.f};
    __builtin_amdgcn_s_setprio(1);
    #pragma unroll
    for (int kb = 0; kb < 8; ++kb){
      int ko = kb*32 + lk*8;
      f16x8 bh = *(const f16x8*)&ftF[(pq*16 + l15)*FT_STRIDE + ko];
      #pragma unroll
      for (int f = 0; f < 5; ++f){
        f16x8 ah = *(const f16x8*)&clsL[(nbase + f*16 + l15)*CL_STRIDE + ko];
        acc[f] = MFMA16F(ah, bh, acc[f], 0, 0, 0);
      }
    }
    __builtin_amdgcn_s_setprio(0);
    // ---- write S to global (drains in background — barriers no longer wait on it)
    #pragma unroll
    for (int f = 0; f < 5; ++f){
      #pragma unroll
      for (int r = 0; r < 4; ++r){
        int n = nbase + f*16 + 4*lk + r;
        Sb[(size_t)n*HW + p0 + col] = f2h(acc[f][r]);
      }
    }
    // ---- row (cls) stats: packed-f16 butterflies
    #pragma unroll
    for (int f = 0; f < 5; ++f){
      #pragma unroll
      for (int rp = 0; rp < 2; ++rp){
        float v0 = acc[f][rp*2], v1 = acc[f][rp*2 + 1];
        f16x2 pm_ = {(_Float16)v0, (_Float16)v1};
        pm_ = __builtin_elementwise_max(pm_, shfl_h2(pm_, 1));
        pm_ = __builtin_elementwise_max(pm_, shfl_h2(pm_, 2));
        pm_ = __builtin_elementwise_max(pm_, shfl_h2(pm_, 4));
        pm_ = __builtin_elementwise_max(pm_, shfl_h2(pm_, 8));
        float m0 = (float)pm_[0], m1 = (float)pm_[1];
        f16x2 ps_ = {(_Float16)__expf(v0 - m0), (_Float16)__expf(v1 - m1)};
        ps_ = ps_ + shfl_h2(ps_, 1);
        ps_ = ps_ + shfl_h2(ps_, 2);
        ps_ = ps_ + shfl_h2(ps_, 4);
        ps_ = ps_ + shfl_h2(ps_, 8);
        if (l15 == f){
          int n0 = nbase + f*16 + 4*lk + rp*2;
          rowM[n0*4 + pq]       = m0;
          rowM[(n0 + 1)*4 + pq] = m1;
          rowS[n0*4 + pq]       = (float)ps_[0];
          rowS[(n0 + 1)*4 + pq] = (float)ps_[1];
        }
      }
    }
    // ---- pixel (pos) max: in-lane + shfl over lk
    {
      float pmax = -3.0e38f;
      #pragma unroll
      for (int f = 0; f < 5; ++f)
        #pragma unroll
        for (int r = 0; r < 4; ++r){
          int n = nbase + 16*f + 4*lk + r;
          if (n < NCLS) pmax = fmaxf(pmax, acc[f][r]);
        }
      pmax = fmaxf(pmax, __shfl_xor(pmax, 16));
      pmax = fmaxf(pmax, __shfl_xor(pmax, 32));
      if (lk == 0) pmx[nh*64 + col] = pmax;
    }
    BAR_LDS();   // B_c: pmx + rowM/rowS ready
    // ---- combine row stats -> rowP (t<160)
    if (t < NPAD){
      float rm0 = rowM[t*4+0], rm1 = rowM[t*4+1], rm2 = rowM[t*4+2], rm3 = rowM[t*4+3];
      float msub = fmaxf(fmaxf(rm0, rm1), fmaxf(rm2, rm3));
      float l = rowS[t*4+0]*__expf(rm0 - msub) + rowS[t*4+1]*__expf(rm1 - msub)
              + rowS[t*4+2]*__expf(rm2 - msub) + rowS[t*4+3]*__expf(rm3 - msub);
      float* rp = rowP + ((size_t)(b*256 + ch*4 + tl)*NPAD + t)*2;
      rp[0] = msub;
      rp[1] = l;
    }
    // ---- exp in-register, write E^T (exponentiated), z-reduce -> pzs
    {
      float mp_ = fmaxf(pmx[col], pmx[64 + col]);
      float s = 0.f;
      #pragma unroll
      for (int f = 0; f < 5; ++f){
        u16x4 ev;
        #pragma unroll
        for (int r = 0; r < 4; ++r){
          int n = nbase + 16*f + 4*lk + r;
          float e = (n < NCLS) ? __expf(acc[f][r] - mp_) : 0.f;
          s += e;
          ev[r] = f2h(e);
        }
        *(u16x4*)&E[col*W_STRIDE + nbase + 16*f + 4*lk] = ev;
      }
      s += __shfl_xor(s, 16);
      s += __shfl_xor(s, 32);
      if (lk == 0) pzs[nh*64 + col] = s;
    }
    BAR_LDS();   // B_d: E(exp) + pzs ready
    // ---- rz (t<64) concurrent with out1-GEMM
    if (t < 64) rzL[t] = 1.0f / (pzs[t] + pzs[64 + t]);
    f32x4 accO[2][4];
    #pragma unroll
    for (int cf = 0; cf < 2; ++cf)
      #pragma unroll
      for (int pfi = 0; pfi < 4; ++pfi) accO[cf][pfi] = (f32x4){0.f,0.f,0.f,0.f};
    __builtin_amdgcn_s_setprio(1);
    #pragma unroll
    for (int kb = 0; kb < 5; ++kb){
      int ko = kb*32 + lk*8;
      #pragma unroll
      for (int pfi = 0; pfi < 4; ++pfi){
        f16x8 bb = *(const f16x8*)&E[(pfi*16 + l15)*W_STRIDE + ko];
        accO[0][pfi] = MFMA16F(aw0[kb], bb, accO[0][pfi], 0, 0, 0);
        accO[1][pfi] = MFMA16F(aw1[kb], bb, accO[1][pfi], 0, 0, 0);
      }
    }
    __builtin_amdgcn_s_setprio(0);
    BAR_LDS();   // B_e: rzL visible
    // ---- epilogue: scale by 1/Z, add f16 feat residual from ftF
    #pragma unroll
    for (int cf = 0; cf < 2; ++cf){
      #pragma unroll
      for (int r = 0; r < 4; ++r){
        int c = cstrip + cf*16 + lk*4 + r;
        float* ob = out1 + (size_t)(b*CDIM + c)*HW + p0;
        #pragma unroll
        for (int pfi = 0; pfi < 4; ++pfi){
          int pp = pfi*16 + l15;
          ob[pp] = accO[cf][pfi][r]*rzL[pp] + h2f(ftF[pp*FT_STRIDE + c]);
        }
      }
    }
  }
}

// ---------------- kComb: reduce 256 tile row-partials -> m_g, rZ (2-level)
__global__ __launch_bounds__(256) void kComb(const float* __restrict__ rowP,
                                             float* __restrict__ mg, float* __restrict__ rz){
  int b = blockIdx.x / 10, nb = blockIdx.x % 10, t = threadIdx.x;
  int sg = t >> 4, j = t & 15;
  int n = nb*16 + j;
  __shared__ float pm[16][17], pl[16][17];
  float m = -3.0e38f, l = 0.f;
  for (int i = 0; i < 16; ++i){
    int s = sg*16 + i;
    const float* rp = rowP + ((size_t)(b*256 + s)*NPAD + n)*2;
    float ms = rp[0], ls = rp[1];
    float mn = fmaxf(m, ms);
    l = l*__expf(m - mn) + ls*__expf(ms - mn);
    m = mn;
  }
  pm[sg][j] = m;
  pl[sg][j] = l;
  __syncthreads();
  if (sg == 0){
    float M = pm[0][j], L = pl[0][j];
    #pragma unroll
    for (int k = 1; k < 16; ++k){
      float ms = pm[k][j], ls = pl[k][j];
      float mn = fmaxf(M, ms);
      L = L*__expf(M - mn) + ls*__expf(ms - mn);
      M = mn;
    }
    mg[b*NPAD + n] = M;
    rz[b*NPAD + n] = 1.0f / L;
  }
}

// ---------------- kOut0 v3: c-split + lgkmcnt-only barriers
__global__ __launch_bounds__(512) void kOut0(const u16* __restrict__ Sg, const float* __restrict__ feat,
                                             const float* __restrict__ mg, u16* __restrict__ part){
  extern __shared__ char sm[];
  u16* Ep = (u16*)sm;                        // [NPAD][EP_STRIDE]
  u16* fN = (u16*)(sm + NPAD*EP_STRIDE*2);   // [128][FN_STRIDE]
  int b = blockIdx.x & 7, pr = (blockIdx.x >> 3) & 31, ch = (blockIdx.x >> 8) & 1;
  int t = threadIdx.x;
  const u16* Sb = Sg + (size_t)b*NPAD*HW;
  const float* featB = feat + (size_t)b*CDIM*HW;
  const float* mgB = mg + b*NPAD;
  int lane = t & 63, wv = t >> 6;
  int l15 = lane & 15, lk = (lane >> 4) & 3;
  int cstrip = wv*16;
  int rr = t >> 3, px8 = (t & 7)*8;
  f32x4 acc[10];
  #pragma unroll
  for (int nf = 0; nf < 10; ++nf) acc[nf] = (f32x4){0.f,0.f,0.f,0.f};
  for (int ck = 0; ck < 8; ++ck){
    int p0 = pr*512 + ck*64;
    #pragma unroll
    for (int ps = 0; ps < 3; ++ps){
      int rowi = ps*64 + rr;
      if (rowi < NPAD){
        u16x8 v = *(const u16x8*)&Sb[(size_t)rowi*HW + p0 + px8];
        float m = mgB[rowi];
        u16x8 o;
        #pragma unroll
        for (int j = 0; j < 8; ++j) o[j] = f2h(__expf(h2f(v[j]) - m));
        *(u16x8*)&Ep[rowi*EP_STRIDE + px8] = o;
      }
    }
    #pragma unroll
    for (int ps = 0; ps < 2; ++ps){
      int cl = ps*64 + rr;
      const float* g = featB + (size_t)(ch*128 + cl)*HW + p0 + px8;
      f32x4 v0 = *(const f32x4*)&g[0];
      f32x4 v1 = *(const f32x4*)&g[4];
      u16x8 o = {f2h(v0[0]), f2h(v0[1]), f2h(v0[2]), f2h(v0[3]),
                 f2h(v1[0]), f2h(v1[1]), f2h(v1[2]), f2h(v1[3])};
      *(u16x8*)&fN[cl*FN_STRIDE + px8] = o;
    }
    BAR_LDS();
    __builtin_amdgcn_s_setprio(1);
    #pragma unroll
    for (int kb = 0; kb < 2; ++kb){
      int ko = kb*32 + lk*8;
      f16x8 a0 = *(const f16x8*)&fN[(cstrip + l15)*FN_STRIDE + ko];
      #pragma unroll
      for (int nf = 0; nf < 10; ++nf){
        f16x8 bb = *(const f16x8*)&Ep[(nf*16 + l15)*EP_STRIDE + ko];
        acc[nf] = MFMA16F(a0, bb, acc[nf], 0, 0, 0);
      }
    }
    __builtin_amdgcn_s_setprio(0);
    BAR_LDS();
  }
  #pragma unroll
  for (int nf = 0; nf < 10; ++nf){
    #pragma unroll
    for (int r = 0; r < 4; ++r){
      int c = ch*128 + cstrip + lk*4 + r;
      int n = nf*16 + l15;
      part[((size_t)(b*32 + pr)*CDIM + c)*NPAD + n] = f2h(acc[nf][r]);
    }
  }
}

// ---------------- k4a: streaming reduce of part over 32 chunks, fold rZ -> combT[b][n][c] f16
__global__ __launch_bounds__(256) void k4a(const u16* __restrict__ part, const float* __restrict__ rz,
                                           u16* __restrict__ combT){
  int b = blockIdx.x / 20, sub = blockIdx.x % 20, t = threadIdx.x;
  int idx8 = (sub*256 + t)*8;
  int c = idx8 / NPAD, n0 = idx8 % NPAD;
  const u16* base = part + (size_t)(b*32)*CDIM*NPAD + idx8;
  float a[8];
  #pragma unroll
  for (int j = 0; j < 8; ++j) a[j] = 0.f;
  for (int s = 0; s < 32; ++s){
    u16x8 v = *(const u16x8*)&base[(size_t)s*CDIM*NPAD];
    #pragma unroll
    for (int j = 0; j < 8; ++j) a[j] += h2f(v[j]);
  }
  const float* rzB = rz + b*NPAD + n0;
  #pragma unroll
  for (int j = 0; j < 8; ++j){
    combT[((size_t)(b*NPAD) + n0 + j)*CDIM + c] = f2h(a[j] * rzB[j]);
  }
}

// ---------------- k4b: out0[n][c] = cls + combT[n][:] @ WcF[c][:]  (MFMA, 80 n-rows/block)
__global__ __launch_bounds__(512) void k4b(const u16* __restrict__ combT, const u16* __restrict__ WcF,
                                           const float* __restrict__ cls, float* __restrict__ out0){
  extern __shared__ char sm[];
  u16* A = (u16*)sm;   // [80][CT_STRIDE]
  int b = blockIdx.x >> 1, nb = blockIdx.x & 1, t = threadIdx.x;
  const u16* cb = combT + (size_t)(b*NPAD + nb*80)*CDIM;
  #pragma unroll
  for (int it = 0; it < 10; ++it){
    int idx8 = (it*512 + t)*8;
    if (idx8 < 80*256){
      int row = idx8 >> 8, k0 = idx8 & 255;
      u16x8 v = *(const u16x8*)&cb[idx8];
      *(u16x8*)&A[row*CT_STRIDE + k0] = v;
    }
  }
  __syncthreads();
  int lane = t & 63, wv = t >> 6;
  int l15 = lane & 15, lk = (lane >> 4) & 3;
  int cstrip = wv*32;
  f32x4 acc[5][2];
  #pragma unroll
  for (int f = 0; f < 5; ++f)
    #pragma unroll
    for (int ct = 0; ct < 2; ++ct) acc[f][ct] = (f32x4){0.f,0.f,0.f,0.f};
  #pragma unroll
  for (int kb = 0; kb < 8; ++kb){
    int ko = kb*32 + lk*8;
    f16x8 b0 = *(const f16x8*)&WcF[(cstrip + l15)*CDIM + ko];
    f16x8 b1 = *(const f16x8*)&WcF[(cstrip + 16 + l15)*CDIM + ko];
    #pragma unroll
    for (int f = 0; f < 5; ++f){
      f16x8 af = *(const f16x8*)&A[(f*16 + l15)*CT_STRIDE + ko];
      acc[f][0] = MFMA16F(af, b0, acc[f][0], 0, 0, 0);
      acc[f][1] = MFMA16F(af, b1, acc[f][1], 0, 0, 0);
    }
  }
  #pragma unroll
  for (int f = 0; f < 5; ++f){
    #pragma unroll
    for (int r = 0; r < 4; ++r){
      int n = nb*80 + f*16 + lk*4 + r;
      if (n < NCLS){
        #pragma unroll
        for (int ct = 0; ct < 2; ++ct){
          int c = cstrip + ct*16 + l15;
          out0[(size_t)(b*NCLS + n)*CDIM + c] = cls[(size_t)(b*NCLS + n)*CDIM + c] + acc[f][ct][r];
        }
      }
    }
  }
}

extern "C" void kernel_launch(void* const* d_in, const int* in_sizes, int n_in,
                              void* d_out, int out_size, void* d_ws, size_t ws_size,
                              hipStream_t stream){
  (void)in_sizes; (void)n_in; (void)out_size; (void)ws_size;
  const float* cls  = (const float*)d_in[0];   // [8][150][256]
  const float* feat = (const float*)d_in[1];   // [8][256][16384]
  const float* Wc   = (const float*)d_in[2];   // [256][256]
  const float* Wf   = (const float*)d_in[3];   // [256][256]
  float* out0 = (float*)d_out;                 // [8][150][256]
  float* out1 = out0 + 8*NCLS*CDIM;            // [8][256][16384]
  char* ws = (char*)d_ws;
  u16*   clsF   = (u16*)(ws + WS_CLSF);
  u16*   clsWT  = (u16*)(ws + WS_CLSWT);
  float* mgv    = (float*)(ws + WS_MG);
  float* rzv    = (float*)(ws + WS_RZ);
  u16*   WcFv   = (u16*)(ws + WS_WCF);
  u16*   combTv = (u16*)(ws + WS_COMBT);
  float* rowPv  = (float*)(ws + WS_ROWP);
  u16*   partv  = (u16*)(ws + WS_PART);
  u16*   Sgp    = (u16*)(ws + WS_S);

  (void)hipFuncSetAttribute((const void*)kSO1, hipFuncAttributeMaxDynamicSharedMemorySize, SO_LDS);

  k0   <<<8*NPAD + 64, 256, 0, stream>>>(cls, Wf, Wc, clsF, clsWT, WcFv);
  kSO1 <<<512, 512, SO_LDS, stream>>>(feat, clsF, clsWT, Sgp, rowPv, out1);
  kComb<<<80, 256, 0, stream>>>(rowPv, mgv, rzv);
  kOut0<<<512, 512, O0_LDS, stream>>>(Sgp, feat, mgv, partv);
  k4a  <<<160, 256, 0, stream>>>(partv, rzv, combTv);
  k4b  <<<16, 512, 80*CT_STRIDE*2, stream>>>(combTv, WcFv, cls, out0);
}

// Round 18
// 183.822 us; speedup vs baseline: 1.2539x; 1.0430x over previous
//
#include <hip/hip_runtime.h>

typedef unsigned short u16;
typedef __attribute__((ext_vector_type(8))) _Float16 f16x8;
typedef __attribute__((ext_vector_type(2))) _Float16 f16x2;
typedef __attribute__((ext_vector_type(4))) float f32x4;
typedef __attribute__((ext_vector_type(4))) unsigned short u16x4;
typedef __attribute__((ext_vector_type(8))) unsigned short u16x8;

#define MFMA16F __builtin_amdgcn_mfma_f32_16x16x32_f16

// barrier that waits LDS ops only — global stores / prefetch loads stay in flight
#define BAR_LDS() do{ asm volatile("s_waitcnt lgkmcnt(0)" ::: "memory"); \
                      __builtin_amdgcn_s_barrier(); }while(0)

#define HW   16384
#define NCLS 150
#define NPAD 160
#define CDIM 256

// LDS strides (shorts)
#define FT_STRIDE 264   // ftF [64 px][256 c]
#define CL_STRIDE 264   // clsL [160 n][256 c] (resident)
#define FN_STRIDE 72    // featN [c][64 px]
#define EP_STRIDE 72    // E'    [160 n][64 px]
#define W_STRIDE  168   // E [64 px][160 n]; clsWT rows
#define CT_STRIDE 264   // combT tile [80 n][256 k]

// kSO1 v7 LDS layout (bytes): 145920 -> 1 block/CU (cls resident)
#define SO_CL   0        // clsL [160][264] u16 = 84480
#define SO_FT   84480    // ftF [64][264] u16 = 33792
#define SO_E    118272   // E [64][168] u16 = 21504
#define SO_ROWM 139776   // [160][4] f32 = 2560
#define SO_ROWS 142336   // [160][4] f32 = 2560
#define SO_PMX  144896   // [2][64] f32 = 512
#define SO_PZS  145408   // [2][64] f32 = 512
#define SO_LDS  145920

// kOut0 LDS (bytes): Ep 23040 + fN-half 18432 = 41472 -> 3 blocks/CU
#define O0_LDS  (NPAD*EP_STRIDE*2 + 128*FN_STRIDE*2)

// workspace offsets (bytes)
#define WS_CLSF  0          // [8][160][256] f16
#define WS_CLSWT 655360     // [8][256][160] f16
#define WS_MG    2359296    // [8][160] f32
#define WS_RZ    2364416    // [8][160] f32
#define WS_WCF   2369536    // [256][256] f16
#define WS_COMBT 2500608    // [8][160][256] f16
#define WS_ROWP  3155968    // [8][256][160][2] f32 (part aliases after kComb)
#define WS_PART  3155968    // [8][32][256][160] f16 (written later by kOut0)
#define WS_S     24127488   // [8][160][16384] f16

__device__ __forceinline__ u16 f2h(float f){ return __builtin_bit_cast(u16, (_Float16)f); }
__device__ __forceinline__ float h2f(u16 h){ return (float)__builtin_bit_cast(_Float16, h); }
__device__ __forceinline__ f16x2 shfl_h2(f16x2 v, int m){
  int x = __builtin_bit_cast(int, v);
  x = __shfl_xor(x, m);
  return __builtin_bit_cast(f16x2, x);
}

// ---------------- k0: cls -> f16 + clsWT = (cls @ Wf^T)^T f16; tail blocks: Wc -> f16
__global__ __launch_bounds__(256) void k0(const float* __restrict__ cls, const float* __restrict__ Wf,
                                          const float* __restrict__ Wc,
                                          u16* __restrict__ clsF, u16* __restrict__ clsWT,
                                          u16* __restrict__ WcF){
  int t = threadIdx.x;
  if (blockIdx.x >= 8*NPAD){
    int i = ((blockIdx.x - 8*NPAD)*256 + t)*4;
    f32x4 v = *(const f32x4*)&Wc[i];
    u16x4 o = {f2h(v[0]), f2h(v[1]), f2h(v[2]), f2h(v[3])};
    *(u16x4*)&WcF[i] = o;
    return;
  }
  int b = blockIdx.x / NPAD, n = blockIdx.x % NPAD;
  __shared__ float row[256];
  int bn = b*NPAD + n;
  if (n < NCLS){
    float v = cls[(b*NCLS + n)*CDIM + t];
    clsF[bn*CDIM + t] = f2h(v);
    row[t] = v;
    __syncthreads();
    float acc = 0.f;
    const float* wr = Wf + t*CDIM;
    #pragma unroll 4
    for (int c = 0; c < 256; c += 4){
      acc += row[c]*wr[c] + row[c+1]*wr[c+1] + row[c+2]*wr[c+2] + row[c+3]*wr[c+3];
    }
    clsWT[(b*CDIM + t)*NPAD + n] = f2h(acc);
  } else {
    clsF[bn*CDIM + t] = 0;
    clsWT[(b*CDIM + t)*NPAD + n] = 0;
  }
}

// ---------------- kSO1 v7: 256 blocks (8 tiles each, one prologue/CU), 4 barriers/tile
__global__ __launch_bounds__(512) void kSO1(const float* __restrict__ feat,
                                            const u16* __restrict__ clsF,
                                            const u16* __restrict__ clsWT,
                                            u16* __restrict__ Sg, float* __restrict__ rowP,
                                            float* __restrict__ out1){
  extern __shared__ char sm[];
  u16*  clsL = (u16*)(sm + SO_CL);
  u16*  ftF  = (u16*)(sm + SO_FT);
  u16*  E    = (u16*)(sm + SO_E);
  float* rowM = (float*)(sm + SO_ROWM);
  float* rowS = (float*)(sm + SO_ROWS);
  float* pmx  = (float*)(sm + SO_PMX);
  float* pzs  = (float*)(sm + SO_PZS);

  int b = blockIdx.x & 7, ch = blockIdx.x >> 3, t = threadIdx.x;
  const float* featG = feat + (size_t)b*CDIM*HW;
  const u16* clsB  = clsF  + b*NPAD*CDIM;
  const u16* clsWB = clsWT + b*CDIM*NPAD;
  u16* Sb = Sg + (size_t)b*NPAD*HW;

  int lane = t & 63, wv = t >> 6;
  int l15 = lane & 15, lk = (lane >> 4) & 3;
  int nh = wv >> 2, pq = wv & 3;
  int nbase = nh*80;
  int col = pq*16 + l15;
  int cstrip = wv*32;
  int p = t & 63, cg = t >> 6;

  // ---- prologue (ONCE per CU): stage clsL, preload clsWT frags, load tile-0 feat
  #pragma unroll
  for (int it = 0; it < 10; ++it){
    int idx8 = (it*512 + t)*8;
    int n = idx8 >> 8, c = idx8 & 255;
    u16x8 v = *(const u16x8*)&clsB[idx8];
    *(u16x8*)&clsL[n*CL_STRIDE + c] = v;
  }
  f16x8 aw0[5], aw1[5];
  #pragma unroll
  for (int kb = 0; kb < 5; ++kb){
    aw0[kb] = *(const f16x8*)&clsWB[(cstrip + l15)*NPAD + kb*32 + lk*8];
    aw1[kb] = *(const f16x8*)&clsWB[(cstrip + 16 + l15)*NPAD + kb*32 + lk*8];
  }
  #pragma unroll
  for (int kb = 0; kb < 5; ++kb){
    asm volatile("" :: "v"(aw0[kb]), "v"(aw1[kb]));
  }
  f32x4 pf[8];
  {
    int p00 = ch*512;
    #pragma unroll
    for (int i = 0; i < 8; ++i){
      int c0 = (i*8 + cg)*4;
      const float* g0 = featG + (size_t)c0*HW + p00 + p;
      pf[i][0] = g0[0]; pf[i][1] = g0[HW]; pf[i][2] = g0[2*HW]; pf[i][3] = g0[3*HW];
    }
  }

  for (int tl = 0; tl < 8; ++tl){
    int p0 = ch*512 + tl*64;
    BAR_LDS();   // B_a: prior tile's LDS readers done (iter0: clsL writes done)
    // ---- ds_write ftF from prefetched regs; issue next tile's loads
    #pragma unroll
    for (int i = 0; i < 8; ++i){
      int c0 = (i*8 + cg)*4;
      u16x4 hv = {f2h(pf[i][0]), f2h(pf[i][1]), f2h(pf[i][2]), f2h(pf[i][3])};
      *(u16x4*)&ftF[p*FT_STRIDE + c0] = hv;
    }
    if (tl < 7){
      int p0n = p0 + 64;
      #pragma unroll
      for (int i = 0; i < 8; ++i){
        int c0 = (i*8 + cg)*4;
        const float* g0 = featG + (size_t)c0*HW + p0n + p;
        pf[i][0] = g0[0]; pf[i][1] = g0[HW]; pf[i][2] = g0[2*HW]; pf[i][3] = g0[3*HW];
      }
    }
    BAR_LDS();   // B_b: ftF ready
    // ---- S-GEMM: straight 40 MFMA, clsL resident
    f32x4 acc[5];
    #pragma unroll
    for (int f = 0; f < 5; ++f) acc[f] = (f32x4){0.f,0.f,0.f,0.f};
    __builtin_amdgcn_s_setprio(1);
    #pragma unroll
    for (int kb = 0; kb < 8; ++kb){
      int ko = kb*32 + lk*8;
      f16x8 bh = *(const f16x8*)&ftF[(pq*16 + l15)*FT_STRIDE + ko];
      #pragma unroll
      for (int f = 0; f < 5; ++f){
        f16x8 ah = *(const f16x8*)&clsL[(nbase + f*16 + l15)*CL_STRIDE + ko];
        acc[f] = MFMA16F(ah, bh, acc[f], 0, 0, 0);
      }
    }
    __builtin_amdgcn_s_setprio(0);
    // ---- write S to global (drains in background)
    #pragma unroll
    for (int f = 0; f < 5; ++f){
      #pragma unroll
      for (int r = 0; r < 4; ++r){
        int n = nbase + f*16 + 4*lk + r;
        Sb[(size_t)n*HW + p0 + col] = f2h(acc[f][r]);
      }
    }
    // ---- row (cls) stats: packed-f16 butterflies
    #pragma unroll
    for (int f = 0; f < 5; ++f){
      #pragma unroll
      for (int rp = 0; rp < 2; ++rp){
        float v0 = acc[f][rp*2], v1 = acc[f][rp*2 + 1];
        f16x2 pm_ = {(_Float16)v0, (_Float16)v1};
        pm_ = __builtin_elementwise_max(pm_, shfl_h2(pm_, 1));
        pm_ = __builtin_elementwise_max(pm_, shfl_h2(pm_, 2));
        pm_ = __builtin_elementwise_max(pm_, shfl_h2(pm_, 4));
        pm_ = __builtin_elementwise_max(pm_, shfl_h2(pm_, 8));
        float m0 = (float)pm_[0], m1 = (float)pm_[1];
        f16x2 ps_ = {(_Float16)__expf(v0 - m0), (_Float16)__expf(v1 - m1)};
        ps_ = ps_ + shfl_h2(ps_, 1);
        ps_ = ps_ + shfl_h2(ps_, 2);
        ps_ = ps_ + shfl_h2(ps_, 4);
        ps_ = ps_ + shfl_h2(ps_, 8);
        if (l15 == f){
          int n0 = nbase + f*16 + 4*lk + rp*2;
          rowM[n0*4 + pq]       = m0;
          rowM[(n0 + 1)*4 + pq] = m1;
          rowS[n0*4 + pq]       = (float)ps_[0];
          rowS[(n0 + 1)*4 + pq] = (float)ps_[1];
        }
      }
    }
    // ---- pixel (pos) max: in-lane + shfl over lk
    {
      float pmax = -3.0e38f;
      #pragma unroll
      for (int f = 0; f < 5; ++f)
        #pragma unroll
        for (int r = 0; r < 4; ++r){
          int n = nbase + 16*f + 4*lk + r;
          if (n < NCLS) pmax = fmaxf(pmax, acc[f][r]);
        }
      pmax = fmaxf(pmax, __shfl_xor(pmax, 16));
      pmax = fmaxf(pmax, __shfl_xor(pmax, 32));
      if (lk == 0) pmx[nh*64 + col] = pmax;
    }
    BAR_LDS();   // B_c: pmx + rowM/rowS ready
    // ---- combine row stats -> rowP (t<160)
    if (t < NPAD){
      float rm0 = rowM[t*4+0], rm1 = rowM[t*4+1], rm2 = rowM[t*4+2], rm3 = rowM[t*4+3];
      float msub = fmaxf(fmaxf(rm0, rm1), fmaxf(rm2, rm3));
      float l = rowS[t*4+0]*__expf(rm0 - msub) + rowS[t*4+1]*__expf(rm1 - msub)
              + rowS[t*4+2]*__expf(rm2 - msub) + rowS[t*4+3]*__expf(rm3 - msub);
      float* rp = rowP + ((size_t)(b*256 + ch*8 + tl)*NPAD + t)*2;
      rp[0] = msub;
      rp[1] = l;
    }
    // ---- exp in-register, write E^T (exponentiated), z-reduce -> pzs
    {
      float mp_ = fmaxf(pmx[col], pmx[64 + col]);
      float s = 0.f;
      #pragma unroll
      for (int f = 0; f < 5; ++f){
        u16x4 ev;
        #pragma unroll
        for (int r = 0; r < 4; ++r){
          int n = nbase + 16*f + 4*lk + r;
          float e = (n < NCLS) ? __expf(acc[f][r] - mp_) : 0.f;
          s += e;
          ev[r] = f2h(e);
        }
        *(u16x4*)&E[col*W_STRIDE + nbase + 16*f + 4*lk] = ev;
      }
      s += __shfl_xor(s, 16);
      s += __shfl_xor(s, 32);
      if (lk == 0) pzs[nh*64 + col] = s;
    }
    BAR_LDS();   // B_d: E(exp) + pzs ready
    // ---- out1-GEMM
    f32x4 accO[2][4];
    #pragma unroll
    for (int cf = 0; cf < 2; ++cf)
      #pragma unroll
      for (int pfi = 0; pfi < 4; ++pfi) accO[cf][pfi] = (f32x4){0.f,0.f,0.f,0.f};
    __builtin_amdgcn_s_setprio(1);
    #pragma unroll
    for (int kb = 0; kb < 5; ++kb){
      int ko = kb*32 + lk*8;
      #pragma unroll
      for (int pfi = 0; pfi < 4; ++pfi){
        f16x8 bb = *(const f16x8*)&E[(pfi*16 + l15)*W_STRIDE + ko];
        accO[0][pfi] = MFMA16F(aw0[kb], bb, accO[0][pfi], 0, 0, 0);
        accO[1][pfi] = MFMA16F(aw1[kb], bb, accO[1][pfi], 0, 0, 0);
      }
    }
    __builtin_amdgcn_s_setprio(0);
    // ---- epilogue: rz computed per-lane from pzs (stable since B_d — no barrier needed)
    float rz4[4];
    #pragma unroll
    for (int pfi = 0; pfi < 4; ++pfi){
      int pp = pfi*16 + l15;
      rz4[pfi] = 1.0f / (pzs[pp] + pzs[64 + pp]);
    }
    #pragma unroll
    for (int cf = 0; cf < 2; ++cf){
      #pragma unroll
      for (int r = 0; r < 4; ++r){
        int c = cstrip + cf*16 + lk*4 + r;
        float* ob = out1 + (size_t)(b*CDIM + c)*HW + p0;
        #pragma unroll
        for (int pfi = 0; pfi < 4; ++pfi){
          int pp = pfi*16 + l15;
          ob[pp] = accO[cf][pfi][r]*rz4[pfi] + h2f(ftF[pp*FT_STRIDE + c]);
        }
      }
    }
  }
}

// ---------------- kComb: reduce 256 tile row-partials -> m_g, rZ (2-level)
__global__ __launch_bounds__(256) void kComb(const float* __restrict__ rowP,
                                             float* __restrict__ mg, float* __restrict__ rz){
  int b = blockIdx.x / 10, nb = blockIdx.x % 10, t = threadIdx.x;
  int sg = t >> 4, j = t & 15;
  int n = nb*16 + j;
  __shared__ float pm[16][17], pl[16][17];
  float m = -3.0e38f, l = 0.f;
  for (int i = 0; i < 16; ++i){
    int s = sg*16 + i;
    const float* rp = rowP + ((size_t)(b*256 + s)*NPAD + n)*2;
    float ms = rp[0], ls = rp[1];
    float mn = fmaxf(m, ms);
    l = l*__expf(m - mn) + ls*__expf(ms - mn);
    m = mn;
  }
  pm[sg][j] = m;
  pl[sg][j] = l;
  __syncthreads();
  if (sg == 0){
    float M = pm[0][j], L = pl[0][j];
    #pragma unroll
    for (int k = 1; k < 16; ++k){
      float ms = pm[k][j], ls = pl[k][j];
      float mn = fmaxf(M, ms);
      L = L*__expf(M - mn) + ls*__expf(ms - mn);
      M = mn;
    }
    mg[b*NPAD + n] = M;
    rz[b*NPAD + n] = 1.0f / L;
  }
}

// ---------------- kOut0: c-split (512 blocks, 3/CU) + lgkmcnt-only barriers
__global__ __launch_bounds__(512) void kOut0(const u16* __restrict__ Sg, const float* __restrict__ feat,
                                             const float* __restrict__ mg, u16* __restrict__ part){
  extern __shared__ char sm[];
  u16* Ep = (u16*)sm;                        // [NPAD][EP_STRIDE]
  u16* fN = (u16*)(sm + NPAD*EP_STRIDE*2);   // [128][FN_STRIDE]
  int b = blockIdx.x & 7, pr = (blockIdx.x >> 3) & 31, ch = (blockIdx.x >> 8) & 1;
  int t = threadIdx.x;
  const u16* Sb = Sg + (size_t)b*NPAD*HW;
  const float* featB = feat + (size_t)b*CDIM*HW;
  const float* mgB = mg + b*NPAD;
  int lane = t & 63, wv = t >> 6;
  int l15 = lane & 15, lk = (lane >> 4) & 3;
  int cstrip = wv*16;
  int rr = t >> 3, px8 = (t & 7)*8;
  f32x4 acc[10];
  #pragma unroll
  for (int nf = 0; nf < 10; ++nf) acc[nf] = (f32x4){0.f,0.f,0.f,0.f};
  for (int ck = 0; ck < 8; ++ck){
    int p0 = pr*512 + ck*64;
    #pragma unroll
    for (int ps = 0; ps < 3; ++ps){
      int rowi = ps*64 + rr;
      if (rowi < NPAD){
        u16x8 v = *(const u16x8*)&Sb[(size_t)rowi*HW + p0 + px8];
        float m = mgB[rowi];
        u16x8 o;
        #pragma unroll
        for (int j = 0; j < 8; ++j) o[j] = f2h(__expf(h2f(v[j]) - m));
        *(u16x8*)&Ep[rowi*EP_STRIDE + px8] = o;
      }
    }
    #pragma unroll
    for (int ps = 0; ps < 2; ++ps){
      int cl = ps*64 + rr;
      const float* g = featB + (size_t)(ch*128 + cl)*HW + p0 + px8;
      f32x4 v0 = *(const f32x4*)&g[0];
      f32x4 v1 = *(const f32x4*)&g[4];
      u16x8 o = {f2h(v0[0]), f2h(v0[1]), f2h(v0[2]), f2h(v0[3]),
                 f2h(v1[0]), f2h(v1[1]), f2h(v1[2]), f2h(v1[3])};
      *(u16x8*)&fN[cl*FN_STRIDE + px8] = o;
    }
    BAR_LDS();
    __builtin_amdgcn_s_setprio(1);
    #pragma unroll
    for (int kb = 0; kb < 2; ++kb){
      int ko = kb*32 + lk*8;
      f16x8 a0 = *(const f16x8*)&fN[(cstrip + l15)*FN_STRIDE + ko];
      #pragma unroll
      for (int nf = 0; nf < 10; ++nf){
        f16x8 bb = *(const f16x8*)&Ep[(nf*16 + l15)*EP_STRIDE + ko];
        acc[nf] = MFMA16F(a0, bb, acc[nf], 0, 0, 0);
      }
    }
    __builtin_amdgcn_s_setprio(0);
    BAR_LDS();
  }
  #pragma unroll
  for (int nf = 0; nf < 10; ++nf){
    #pragma unroll
    for (int r = 0; r < 4; ++r){
      int c = ch*128 + cstrip + lk*4 + r;
      int n = nf*16 + l15;
      part[((size_t)(b*32 + pr)*CDIM + c)*NPAD + n] = f2h(acc[nf][r]);
    }
  }
}

// ---------------- k4a: streaming reduce of part over 32 chunks, fold rZ -> combT[b][n][c] f16
__global__ __launch_bounds__(256) void k4a(const u16* __restrict__ part, const float* __restrict__ rz,
                                           u16* __restrict__ combT){
  int b = blockIdx.x / 20, sub = blockIdx.x % 20, t = threadIdx.x;
  int idx8 = (sub*256 + t)*8;
  int c = idx8 / NPAD, n0 = idx8 % NPAD;
  const u16* base = part + (size_t)(b*32)*CDIM*NPAD + idx8;
  float a[8];
  #pragma unroll
  for (int j = 0; j < 8; ++j) a[j] = 0.f;
  for (int s = 0; s < 32; ++s){
    u16x8 v = *(const u16x8*)&base[(size_t)s*CDIM*NPAD];
    #pragma unroll
    for (int j = 0; j < 8; ++j) a[j] += h2f(v[j]);
  }
  const float* rzB = rz + b*NPAD + n0;
  #pragma unroll
  for (int j = 0; j < 8; ++j){
    combT[((size_t)(b*NPAD) + n0 + j)*CDIM + c] = f2h(a[j] * rzB[j]);
  }
}

// ---------------- k4b: out0[n][c] = cls + combT[n][:] @ WcF[c][:]  (MFMA, 80 n-rows/block)
__global__ __launch_bounds__(512) void k4b(const u16* __restrict__ combT, const u16* __restrict__ WcF,
                                           const float* __restrict__ cls, float* __restrict__ out0){
  extern __shared__ char sm[];
  u16* A = (u16*)sm;   // [80][CT_STRIDE]
  int b = blockIdx.x >> 1, nb = blockIdx.x & 1, t = threadIdx.x;
  const u16* cb = combT + (size_t)(b*NPAD + nb*80)*CDIM;
  #pragma unroll
  for (int it = 0; it < 10; ++it){
    int idx8 = (it*512 + t)*8;
    if (idx8 < 80*256){
      int row = idx8 >> 8, k0 = idx8 & 255;
      u16x8 v = *(const u16x8*)&cb[idx8];
      *(u16x8*)&A[row*CT_STRIDE + k0] = v;
    }
  }
  __syncthreads();
  int lane = t & 63, wv = t >> 6;
  int l15 = lane & 15, lk = (lane >> 4) & 3;
  int cstrip = wv*32;
  f32x4 acc[5][2];
  #pragma unroll
  for (int f = 0; f < 5; ++f)
    #pragma unroll
    for (int ct = 0; ct < 2; ++ct) acc[f][ct] = (f32x4){0.f,0.f,0.f,0.f};
  #pragma unroll
  for (int kb = 0; kb < 8; ++kb){
    int ko = kb*32 + lk*8;
    f16x8 b0 = *(const f16x8*)&WcF[(cstrip + l15)*CDIM + ko];
    f16x8 b1 = *(const f16x8*)&WcF[(cstrip + 16 + l15)*CDIM + ko];
    #pragma unroll
    for (int f = 0; f < 5; ++f){
      f16x8 af = *(const f16x8*)&A[(f*16 + l15)*CT_STRIDE + ko];
      acc[f][0] = MFMA16F(af, b0, acc[f][0], 0, 0, 0);
      acc[f][1] = MFMA16F(af, b1, acc[f][1], 0, 0, 0);
    }
  }
  #pragma unroll
  for (int f = 0; f < 5; ++f){
    #pragma unroll
    for (int r = 0; r < 4; ++r){
      int n = nb*80 + f*16 + lk*4 + r;
      if (n < NCLS){
        #pragma unroll
        for (int ct = 0; ct < 2; ++ct){
          int c = cstrip + ct*16 + l15;
          out0[(size_t)(b*NCLS + n)*CDIM + c] = cls[(size_t)(b*NCLS + n)*CDIM + c] + acc[f][ct][r];
        }
      }
    }
  }
}

extern "C" void kernel_launch(void* const* d_in, const int* in_sizes, int n_in,
                              void* d_out, int out_size, void* d_ws, size_t ws_size,
                              hipStream_t stream){
  (void)in_sizes; (void)n_in; (void)out_size; (void)ws_size;
  const float* cls  = (const float*)d_in[0];   // [8][150][256]
  const float* feat = (const float*)d_in[1];   // [8][256][16384]
  const float* Wc   = (const float*)d_in[2];   // [256][256]
  const float* Wf   = (const float*)d_in[3];   // [256][256]
  float* out0 = (float*)d_out;                 // [8][150][256]
  float* out1 = out0 + 8*NCLS*CDIM;            // [8][256][16384]
  char* ws = (char*)d_ws;
  u16*   clsF   = (u16*)(ws + WS_CLSF);
  u16*   clsWT  = (u16*)(ws + WS_CLSWT);
  float* mgv    = (float*)(ws + WS_MG);
  float* rzv    = (float*)(ws + WS_RZ);
  u16*   WcFv   = (u16*)(ws + WS_WCF);
  u16*   combTv = (u16*)(ws + WS_COMBT);
  float* rowPv  = (float*)(ws + WS_ROWP);
  u16*   partv  = (u16*)(ws + WS_PART);
  u16*   Sgp    = (u16*)(ws + WS_S);

  (void)hipFuncSetAttribute((const void*)kSO1, hipFuncAttributeMaxDynamicSharedMemorySize, SO_LDS);

  k0   <<<8*NPAD + 64, 256, 0, stream>>>(cls, Wf, Wc, clsF, clsWT, WcFv);
  kSO1 <<<256, 512, SO_LDS, stream>>>(feat, clsF, clsWT, Sgp, rowPv, out1);
  kComb<<<80, 256, 0, stream>>>(rowPv, mgv, rzv);
  kOut0<<<512, 512, O0_LDS, stream>>>(Sgp, feat, mgv, partv);
  k4a  <<<160, 256, 0, stream>>>(partv, rzv, combTv);
  k4b  <<<16, 512, 80*CT_STRIDE*2, stream>>>(combTv, WcFv, cls, out0);
}